// Round 13
// baseline (4328.711 us; speedup 1.0000x reference)
//
#include <hip/hip_runtime.h>
#include <cstdio>

typedef __bf16 bf16x8 __attribute__((ext_vector_type(8)));
typedef float f32x4 __attribute__((ext_vector_type(4)));
typedef int i32x4 __attribute__((ext_vector_type(4)));
typedef unsigned short u16x4 __attribute__((ext_vector_type(4)));

__device__ __forceinline__ float bf2f(unsigned short u) {
  union { unsigned int i; float f; } x; x.i = ((unsigned int)u) << 16; return x.f;
}
__device__ __forceinline__ unsigned short f2bf(float f) {
  union { float f; unsigned int i; } x; x.f = f;
  unsigned int r = x.i + 0x7fffu + ((x.i >> 16) & 1u);
  return (unsigned short)(r >> 16);
}

// async global->LDS, 16B per lane; LDS dest is wave-uniform base + lane*16
__device__ __forceinline__ void gl2lds16(const unsigned short* g, unsigned short* l) {
  __builtin_amdgcn_global_load_lds((const __attribute__((address_space(1))) unsigned int*)g,
                                   (__attribute__((address_space(3))) unsigned int*)l, 16, 0, 0);
}

// ---------------- elementwise f32 -> bf16 cast (vec4) ----------------
__global__ __launch_bounds__(256) void k_cast(const float* __restrict__ in,
                                              unsigned short* __restrict__ out, int n4) {
  int i = blockIdx.x * 256 + threadIdx.x;
  if (i >= n4) return;
  f32x4 v = ((const f32x4*)in)[i];
  u16x4 o;
  o[0] = f2bf(v[0]); o[1] = f2bf(v[1]); o[2] = f2bf(v[2]); o[3] = f2bf(v[3]);
  ((u16x4*)out)[i] = o;
}

// -------- transpose-cast: src f32 [K][N] -> dst bf16 [N][K] --------
__global__ __launch_bounds__(256) void k_tcast(const float* __restrict__ src,
                                               unsigned short* __restrict__ dst,
                                               int K, int N) {
  __shared__ float tile[32][33];
  int gx = blockIdx.x * 32;  // N dim
  int gy = blockIdx.y * 32;  // K dim
  int t = threadIdx.x;
  int c = t & 31, r0 = t >> 5;
#pragma unroll
  for (int i = 0; i < 4; i++) {
    int r = r0 + i * 8;
    tile[r][c] = src[(size_t)(gy + r) * N + gx + c];
  }
  __syncthreads();
#pragma unroll
  for (int i = 0; i < 4; i++) {
    int r = r0 + i * 8;
    dst[(size_t)(gx + r) * K + gy + c] = f2bf(tile[c][r]);
  }
}

// ---- folded bias: out[n] = bv[n] + sum_j bk[j]*wv[j][n]  (f32, 1024 wide) ----
__global__ __launch_bounds__(256) void k_bfold(const float* __restrict__ bk,
                                               const float* __restrict__ wv,
                                               const float* __restrict__ bv,
                                               float* __restrict__ out) {
  int n = blockIdx.x * 256 + threadIdx.x;
  float acc = bv[n];
#pragma unroll 8
  for (int j = 0; j < 1024; j++) acc += bk[j] * wv[(size_t)j * 1024 + n];
  out[n] = acc;
}

// ---- concat two 1024-f32 vectors into out[0..2047] ----
__global__ __launch_bounds__(256) void k_cpb(const float* __restrict__ a,
                                             const float* __restrict__ b,
                                             float* __restrict__ out) {
  int t = blockIdx.x * 256 + threadIdx.x;
  out[t] = a[t];
  out[1024 + t] = b[t];
}

// ---- cs-fold: BtQK[n=(h*16+s)][k] = sum_e wqT[h*64+e][k]*K[s][h*64+e]; bqk[n]=bq.K ----
__global__ __launch_bounds__(256) void k_wqk(const unsigned short* __restrict__ wqT,
                                             const float* __restrict__ bq,
                                             const unsigned short* __restrict__ Kcs,
                                             unsigned short* __restrict__ BtQK,
                                             float* __restrict__ bqk) {
  int n = blockIdx.x, h = n >> 4, s = n & 15, t = threadIdx.x;
  if (s >= 10) {
    ((u16x4*)(BtQK + (size_t)n * 1024))[t] = u16x4{0, 0, 0, 0};
    if (t == 0) bqk[n] = 0.f;
    return;
  }
  float acc[4] = {0.f, 0.f, 0.f, 0.f};
  for (int e = 0; e < 64; e++) {
    float kv = bf2f(Kcs[s * 1024 + h * 64 + e]);
    u16x4 rv = ((const u16x4*)(wqT + (size_t)(h * 64 + e) * 1024))[t];
#pragma unroll
    for (int i = 0; i < 4; i++) acc[i] += bf2f(rv[i]) * kv;
  }
  u16x4 o;
#pragma unroll
  for (int i = 0; i < 4; i++) o[i] = f2bf(acc[i]);
  ((u16x4*)(BtQK + (size_t)n * 1024))[t] = o;
  if (t == 0) {
    float b = 0.f;
    for (int e = 0; e < 64; e++) b += bq[h * 64 + e] * bf2f(Kcs[s * 1024 + h * 64 + e]);
    bqk[n] = b;
  }
}

// ---- entmax-1.5 over 10 stored patterns, fully in registers (thread = (row,head)) ----
// in SC[M][256] (raw scores, head h at cols h*16+0..9), out A[M][256] normalized, pads 0.
__global__ __launch_bounds__(256) void k_entmax10(const unsigned short* __restrict__ SC,
                                                  unsigned short* __restrict__ A) {
  int t = threadIdx.x;
  int m = blockIdx.x * 16 + (t >> 4), h = t & 15;
  const unsigned short* p = SC + (size_t)m * 256 + h * 16;
  float xs[10], mx = -1e30f;
#pragma unroll
  for (int s = 0; s < 10; s++) { xs[s] = bf2f(p[s]) * 0.0625f; mx = fmaxf(mx, xs[s]); }
  float lo = mx - 1.f, hi = mx - 0.31622776601683794f;  // d^-0.5, d=10
#pragma unroll 1
  for (int it = 0; it < 26; it++) {
    float mid = 0.5f * (lo + hi);
    float f = 0.f;
#pragma unroll
    for (int s = 0; s < 10; s++) { float dd = fmaxf(xs[s] - mid, 0.f); f += dd * dd; }
    bool gt = f > 1.f;
    lo = gt ? mid : lo;
    hi = gt ? hi : mid;
  }
  float tau = 0.5f * (lo + hi), ps = 0.f;
#pragma unroll
  for (int s = 0; s < 10; s++) { float dd = fmaxf(xs[s] - tau, 0.f); xs[s] = dd * dd; ps += xs[s]; }
  float r = 1.f / ps;
  unsigned short* q = A + (size_t)m * 256 + h * 16;
  u16x4 o0, o1, o2, o3;
#pragma unroll
  for (int i = 0; i < 4; i++) o0[i] = f2bf(xs[i] * r);
#pragma unroll
  for (int i = 0; i < 4; i++) o1[i] = f2bf(xs[4 + i] * r);
  o2[0] = f2bf(xs[8] * r); o2[1] = f2bf(xs[9] * r); o2[2] = 0; o2[3] = 0;
  o3[0] = o3[1] = o3[2] = o3[3] = 0;
  ((u16x4*)q)[0] = o0; ((u16x4*)q)[1] = o1; ((u16x4*)q)[2] = o2; ((u16x4*)q)[3] = o3;
}

// ---- PV + Hopfield "mix": out_mix[(b*32+ln)][c] = sum_s A[b,h,l,s] * V[s][h*64+d]
// with h = ln>>1, l = (ln&1)*16 + (c>>6), d = c&63.  One block per output row.
__global__ __launch_bounds__(256) void k_pvmix(const unsigned short* __restrict__ A,
                                               const unsigned short* __restrict__ Vcs,
                                               unsigned short* __restrict__ Out) {
  __shared__ float Vs[10][64];
  __shared__ float Asm[16][10];
  const int row = blockIdx.x;
  const int b = row >> 5, ln = row & 31;
  const int h = ln >> 1, lbase = (ln & 1) * 16;
  const int t = threadIdx.x;
  if (t < 160) {
    int j = t / 10, s = t - j * 10;
    Asm[j][s] = bf2f(A[((size_t)(b * 32 + lbase + j)) * 256 + h * 16 + s]);
  }
  for (int idx = t; idx < 640; idx += 256) {
    int s = idx >> 6, d = idx & 63;
    Vs[s][d] = bf2f(Vcs[s * 1024 + h * 64 + d]);
  }
  __syncthreads();
  const int j = t >> 4, d0 = (t & 15) * 4;
  float acc[4] = {0.f, 0.f, 0.f, 0.f};
#pragma unroll
  for (int s = 0; s < 10; s++) {
    float a = Asm[j][s];
#pragma unroll
    for (int i = 0; i < 4; i++) acc[i] += a * Vs[s][d0 + i];
  }
  u16x4 o;
#pragma unroll
  for (int i = 0; i < 4; i++) o[i] = f2bf(acc[i]);
  ((u16x4*)(Out + (size_t)row * 1024))[t] = o;
}

// ======== MFMA GEMM: BMx256 tile, BK=32, 2-buffer (64/48 KB LDS -> 2-3 blocks/CU) ========
// C[M][N] = A[M][K](bf16 rm) * Bt[N][K]^T + bias (opt exact GELU); bias may be null.
// 512 threads = 8 waves (2m x 4n); wave tile (BM/2) x 64. One-barrier-per-K-step schedule
// (r3-proven): vmcnt(0); __syncthreads; stage(buf^1, j+1); ds_read; MFMA.
// T2 swizzle (64B rows): source chunk (l&3)^((l>>3)&3); read granule g^((ra>>1)&3).
template <int BM, bool GELU>
__global__ __launch_bounds__(512, 4) void k_gemm(const unsigned short* __restrict__ A,
                                                 const unsigned short* __restrict__ Bt,
                                                 const float* __restrict__ bias,
                                                 unsigned short* __restrict__ C,
                                                 int M, int N, int K) {
  constexpr int RPW = BM / 2;   // rows per wave tile
  constexpr int RF = RPW / 16;  // A fragments per wave
  __shared__ unsigned short As[2][BM * 32];
  __shared__ unsigned short Bs[2][256 * 32];
  const int rowA0 = blockIdx.y * BM, colB0 = blockIdx.x * 256;
  const int t = threadIdx.x, w = t >> 6, lane = t & 63;
  const int wm = w >> 2, wn = w & 3;
  const int g = lane >> 4, ra = lane & 15;
  const int gp8 = (g ^ ((ra >> 1) & 3)) * 8;           // read-side inverse swizzle
  const int srow = lane >> 2;                           // 16 rows per staging instr
  const int schunk = ((lane & 3) ^ ((lane >> 3) & 3)) * 8;

  f32x4 acc[RF][4] = {};

  auto stage = [&](int buf, int kk) {
#pragma unroll
    for (int i = 0; i < BM / 128; i++)
      gl2lds16(A + (size_t)(rowA0 + w * 16 + i * 128 + srow) * K + kk + schunk,
               &As[buf][(w * 16 + i * 128) * 32]);
#pragma unroll
    for (int i = 0; i < 2; i++)
      gl2lds16(Bt + (size_t)(colB0 + w * 16 + i * 128 + srow) * K + kk + schunk,
               &Bs[buf][(w * 16 + i * 128) * 32]);
  };

  const int NT = K >> 5;
  stage(0, 0);
  int buf = 0;
  for (int j = 0; j < NT; ++j) {
    asm volatile("s_waitcnt vmcnt(0)" ::: "memory");
    __syncthreads();
    if (j + 1 < NT) stage(buf ^ 1, (j + 1) * 32);
    const unsigned short* Ab = &As[buf][0];
    const unsigned short* Bb = &Bs[buf][0];
    bf16x8 bfr[4];
#pragma unroll
    for (int fc = 0; fc < 4; fc++)
      bfr[fc] = *(const bf16x8*)&Bb[(wn * 64 + fc * 16 + ra) * 32 + gp8];
#pragma unroll
    for (int fr = 0; fr < RF; fr++) {
      bf16x8 af = *(const bf16x8*)&Ab[(wm * RPW + fr * 16 + ra) * 32 + gp8];
#pragma unroll
      for (int fc = 0; fc < 4; fc++)
        acc[fr][fc] = __builtin_amdgcn_mfma_f32_16x16x32_bf16(af, bfr[fc], acc[fr][fc], 0, 0, 0);
    }
    buf ^= 1;
  }
  __syncthreads();  // all reads done before epilogue scratch reuse

  // ---- epilogue: per-wave LDS transpose (XOR-swizzled), 16B coalesced stores ----
  unsigned short* Ep = &As[0][0] + w * 1024;  // 16x64 u16 per wave (spans As[0..1], both free)
  const int grow0 = rowA0 + wm * RPW;
  const int gcol0 = colB0 + wn * 64;
  float bv[4];
#pragma unroll
  for (int n = 0; n < 4; n++) bv[n] = bias ? bias[gcol0 + n * 16 + ra] : 0.f;
  const int rdrow = lane >> 3, rg = lane & 7;
#pragma unroll
  for (int m = 0; m < RF; m++) {
#pragma unroll
    for (int n = 0; n < 4; n++)
#pragma unroll
      for (int i = 0; i < 4; i++) {
        int r = g * 4 + i;
        float v = acc[m][n][i] + bv[n];
        if (GELU) v = 0.5f * v * (1.f + erff(v * 0.70710678118654752f));
        Ep[r * 64 + ((ra + n * 16) ^ ((r & 7) << 3))] = f2bf(v);
      }
    asm volatile("s_waitcnt lgkmcnt(0)" ::: "memory");
    __builtin_amdgcn_sched_barrier(0);
#pragma unroll
    for (int p = 0; p < 2; p++) {
      int rr = p * 8 + rdrow;
      bf16x8 val = *(const bf16x8*)&Ep[rr * 64 + ((rg ^ (rr & 7)) << 3)];
      *(bf16x8*)&C[(size_t)(grow0 + m * 16 + rr) * N + gcol0 + rg * 8] = val;
    }
    asm volatile("s_waitcnt lgkmcnt(0)" ::: "memory");
  }
}

// ======== small MFMA GEMM (folds + skinny cs GEMMs): 128^2 tile, ring-3 ========
__global__ __launch_bounds__(256) void k_gemmS(const unsigned short* __restrict__ A,
                                               const unsigned short* __restrict__ Bt,
                                               const float* __restrict__ bias,
                                               unsigned short* __restrict__ C,
                                               int M, int N, int K) {
  __shared__ unsigned short As[3][128 * 32];
  __shared__ unsigned short Bs[3][128 * 32];
  const int rowA0 = blockIdx.y * 128, colB0 = blockIdx.x * 128;
  const int t = threadIdx.x, w = t >> 6, lane = t & 63;
  const int wr = w >> 1, wc = w & 1;
  const int srow = w * 16 + (lane >> 2);
  const int schunk = (lane & 3) ^ ((lane >> 3) & 3);
  const unsigned short* pa = A + (size_t)(rowA0 + srow) * K + schunk * 8;
  const unsigned short* pb = Bt + (size_t)(colB0 + srow) * K + schunk * 8;
  const size_t row64 = (size_t)64 * K;
  f32x4 acc[4][4] = {};
  const int g = lane >> 4, ra = lane & 15;
  const int gp8 = (g ^ ((ra >> 1) & 3)) * 8;
  auto stage = [&](int buf, int kk) {
    gl2lds16(pa + kk, &As[buf][w * 512]);
    gl2lds16(pa + row64 + kk, &As[buf][2048 + w * 512]);
    gl2lds16(pb + kk, &Bs[buf][w * 512]);
    gl2lds16(pb + row64 + kk, &Bs[buf][2048 + w * 512]);
  };
  const int NT = K >> 5;
  stage(0, 0);
  if (NT > 1) stage(1, 32);
  int cur = 0;
  for (int j = 0; j < NT; ++j) {
    if (j + 1 < NT) asm volatile("s_waitcnt vmcnt(4)" ::: "memory");
    else            asm volatile("s_waitcnt vmcnt(0)" ::: "memory");
    __syncthreads();
    if (j + 2 < NT) { int nb = cur + 2; if (nb >= 3) nb -= 3; stage(nb, (j + 2) * 32); }
    bf16x8 af[4], bfr[4];
#pragma unroll
    for (int m = 0; m < 4; m++)
      af[m] = *(const bf16x8*)&As[cur][(wr * 64 + m * 16 + ra) * 32 + gp8];
#pragma unroll
    for (int n = 0; n < 4; n++)
      bfr[n] = *(const bf16x8*)&Bs[cur][(wc * 64 + n * 16 + ra) * 32 + gp8];
#pragma unroll
    for (int m = 0; m < 4; m++)
#pragma unroll
      for (int n = 0; n < 4; n++)
        acc[m][n] = __builtin_amdgcn_mfma_f32_16x16x32_bf16(af[m], bfr[n], acc[m][n], 0, 0, 0);
    __syncthreads();
    cur += 1; if (cur >= 3) cur -= 3;
  }
  const int cr = g * 4, cc = ra;
#pragma unroll
  for (int m = 0; m < 4; m++) {
    int grow = rowA0 + wr * 64 + m * 16 + cr;
#pragma unroll
    for (int n = 0; n < 4; n++) {
      int gcol = colB0 + wc * 64 + n * 16 + cc;
      float bvv = bias ? bias[gcol] : 0.f;
#pragma unroll
      for (int i = 0; i < 4; i++)
        C[(size_t)(grow + i) * N + gcol] = f2bf(acc[m][n][i] + bvv);
    }
  }
}

// ---------------- small GEMM (M<=10): C[Mr][1024] = A[Mr][1024] * Wt^T + bias ----------------
__global__ __launch_bounds__(256) void k_gemm10(const unsigned short* __restrict__ A,
                                                const unsigned short* __restrict__ Bt,
                                                const float* __restrict__ bias,
                                                unsigned short* __restrict__ C) {
  __shared__ float af[1024];
  int m = blockIdx.x, nb = blockIdx.y;
  int t = threadIdx.x;
#pragma unroll
  for (int i = 0; i < 4; i++) af[t * 4 + i] = bf2f(A[(size_t)m * 1024 + t * 4 + i]);
  __syncthreads();
  int w = t >> 6, lane = t & 63;
  for (int n = nb * 64 + w; n < nb * 64 + 64; n += 4) {
    const unsigned short* brow = Bt + (size_t)n * 1024 + lane * 16;
    float acc = 0.f;
#pragma unroll
    for (int j = 0; j < 16; j++) acc += af[lane * 16 + j] * bf2f(brow[j]);
#pragma unroll
    for (int o = 32; o; o >>= 1) acc += __shfl_xor(acc, o);
    if (lane == 0) C[(size_t)m * 1024 + n] = f2bf(acc + bias[n]);
  }
}

// ---------------- entmax-1.5 attention, MFMA version (RS = input row stride) ----------------
template <int L, int S, bool SHARED>
__global__ __launch_bounds__(256) void k_attn(const unsigned short* __restrict__ Q,
                                              const unsigned short* __restrict__ Kb,
                                              const unsigned short* __restrict__ Vb,
                                              unsigned short* __restrict__ Out, int RS) {
  constexpr int SP = (S <= 32) ? 32 : 64;
  constexpr int QST = 72;
  constexpr int VST = SP + 8;
  constexpr int CST = SP + 4;
  __shared__ unsigned short Qs[L * QST];
  __shared__ unsigned short Ks[SP * QST];
  __shared__ unsigned short Vt[64 * VST];
  __shared__ float Sc[L * CST];
  __shared__ float Rps[L];
  const int blk = blockIdx.x, batch = blk >> 4, h = blk & 15;
  const int t = threadIdx.x, w = t >> 6, lane = t & 63;
  for (int c = t; c < L * 8; c += 256) {
    int r = c >> 3, ch = (c & 7) * 8;
    *(i32x4*)&Qs[r * QST + ch] =
        *(const i32x4*)&Q[((size_t)(batch * L + r)) * RS + h * 64 + ch];
  }
  for (int c = t; c < SP * 8; c += 256) {
    int r = c >> 3, ch = (c & 7) * 8;
    i32x4 v = {0, 0, 0, 0};
    if (r < S) {
      size_t rb = SHARED ? (size_t)r : (size_t)(batch * S + r);
      v = *(const i32x4*)&Kb[rb * RS + h * 64 + ch];
    }
    *(i32x4*)&Ks[r * QST + ch] = v;
  }
  for (int c = t; c < SP * 64; c += 256) {
    int s = c >> 6, e = c & 63;
    unsigned short v = 0;
    if (s < S) {
      size_t rb = SHARED ? (size_t)s : (size_t)(batch * S + s);
      v = Vb[rb * RS + h * 64 + e];
    }
    Vt[e * VST + s] = v;
  }
  __syncthreads();
  const int ka = (lane >> 4) * 8, ra = lane & 15;
  const int cr = (lane >> 4) * 4, cc = lane & 15;
  constexpr int NT = SP / 16, TT = (L / 16) * NT;
  for (int tt = w; tt < TT; tt += 4) {
    int m = tt / NT, n = tt % NT;
    f32x4 a = {0.f, 0.f, 0.f, 0.f};
#pragma unroll
    for (int ks = 0; ks < 2; ks++) {
      bf16x8 af = *(const bf16x8*)&Qs[(m * 16 + ra) * QST + ks * 32 + ka];
      bf16x8 bf = *(const bf16x8*)&Ks[(n * 16 + ra) * QST + ks * 32 + ka];
      a = __builtin_amdgcn_mfma_f32_16x16x32_bf16(af, bf, a, 0, 0, 0);
    }
#pragma unroll
    for (int i = 0; i < 4; i++)
      Sc[(m * 16 + cr + i) * CST + n * 16 + cc] = a[i] * 0.0625f;
  }
  __syncthreads();
  constexpr int G = 256 / L, RW = 64 / G, SL = SP / G;
  const int row = w * RW + lane / G, sub = lane % G;
  float xs[SL];
#pragma unroll
  for (int j = 0; j < SL; j++) {
    int s = sub * SL + j;
    float v = Sc[row * CST + s];
    if (S < SP && s >= S) v = -1e30f;
    xs[j] = v;
  }
  float mx = xs[0];
#pragma unroll
  for (int j = 1; j < SL; j++) mx = fmaxf(mx, xs[j]);
#pragma unroll
  for (int o = G / 2; o; o >>= 1) mx = fmaxf(mx, __shfl_xor(mx, o));
  const float hoff = (S == 64) ? 0.125f : (S == 32) ? 0.17677669529663687f : 0.31622776601683794f;
  float lo = mx - 1.f, hi = mx - hoff;
#pragma unroll 1
  for (int it = 0; it < 26; it++) {
    float mid = 0.5f * (lo + hi);
    float f = 0.f;
#pragma unroll
    for (int j = 0; j < SL; j++) { float dd = fmaxf(xs[j] - mid, 0.f); f += dd * dd; }
#pragma unroll
    for (int o = G / 2; o; o >>= 1) f += __shfl_xor(f, o);
    bool gt = f > 1.f;
    lo = gt ? mid : lo;
    hi = gt ? hi : mid;
  }
  float tau = 0.5f * (lo + hi);
  float ps = 0.f;
#pragma unroll
  for (int j = 0; j < SL; j++) { float dd = fmaxf(xs[j] - tau, 0.f); xs[j] = dd * dd; ps += xs[j]; }
#pragma unroll
  for (int o = G / 2; o; o >>= 1) ps += __shfl_xor(ps, o);
  if (sub == 0) Rps[row] = 1.f / ps;
  unsigned short* Pb = Qs;
#pragma unroll
  for (int j = 0; j < SL; j += 4) {
    u16x4 pv;
#pragma unroll
    for (int jj = 0; jj < 4; jj++) pv[jj] = f2bf(xs[j + jj]);
    *(u16x4*)&Pb[row * VST + sub * SL + j] = pv;
  }
  __syncthreads();
  constexpr int TT2 = (L / 16) * 4;
  for (int tt = w; tt < TT2; tt += 4) {
    int m = tt >> 2, n = tt & 3;
    f32x4 a = {0.f, 0.f, 0.f, 0.f};
#pragma unroll
    for (int ks = 0; ks < SP / 32; ks++) {
      bf16x8 af = *(const bf16x8*)&Pb[(m * 16 + ra) * VST + ks * 32 + ka];
      bf16x8 bf = *(const bf16x8*)&Vt[(n * 16 + ra) * VST + ks * 32 + ka];
      a = __builtin_amdgcn_mfma_f32_16x16x32_bf16(af, bf, a, 0, 0, 0);
    }
#pragma unroll
    for (int i = 0; i < 4; i++) {
      int l = m * 16 + cr + i, e = n * 16 + cc;
      float val = a[i] * Rps[l];
      int l_new = h * (L / 16) + (l >> 4);
      int cg = (l & 15) * 64 + e;
      Out[((size_t)(batch * L + l_new)) * 1024 + cg] = f2bf(val);
    }
  }
}

// ---------------- LayerNorm(a+b) * g + be, optional row permutation / f32 out ----------------
template <int MODE, bool F32OUT>
__global__ __launch_bounds__(256) void k_ln(const unsigned short* __restrict__ a,
                                            const unsigned short* __restrict__ b,
                                            const float* __restrict__ g,
                                            const float* __restrict__ be,
                                            void* __restrict__ outp) {
  __shared__ float red[8];
  int r = blockIdx.x, t = threadIdx.x;
  size_t base = (size_t)r * 1024 + t * 4;
  u16x4 av = *(const u16x4*)(a + base);
  u16x4 bv = *(const u16x4*)(b + base);
  float x[4];
  float s = 0.f, ss = 0.f;
#pragma unroll
  for (int i = 0; i < 4; i++) {
    x[i] = bf2f(av[i]) + bf2f(bv[i]);
    s += x[i]; ss += x[i] * x[i];
  }
#pragma unroll
  for (int o = 32; o; o >>= 1) { s += __shfl_xor(s, o); ss += __shfl_xor(ss, o); }
  int w = t >> 6;
  if ((t & 63) == 0) { red[w] = s; red[4 + w] = ss; }
  __syncthreads();
  s = red[0] + red[1] + red[2] + red[3];
  ss = red[4] + red[5] + red[6] + red[7];
  float mean = s * (1.f / 1024.f);
  float var = ss * (1.f / 1024.f) - mean * mean;
  float rstd = rsqrtf(var + 1e-5f);
  int orow;
  if (MODE == 0) orow = r;
  else if (MODE == 1) { int bi = r >> 11, rem = r & 2047; int tt = rem >> 6, sd = rem & 63; orow = (bi << 11) + sd * 32 + tt; }
  else { int bi = r >> 11, rem = r & 2047; int sd = rem >> 5, tt = rem & 31; orow = (bi << 11) + tt * 64 + sd; }
  size_t ob = (size_t)orow * 1024 + t * 4;
  if (F32OUT) {
    f32x4 y;
#pragma unroll
    for (int i = 0; i < 4; i++) y[i] = (x[i] - mean) * rstd * g[t * 4 + i] + be[t * 4 + i];
    *(f32x4*)((float*)outp + ob) = y;
  } else {
    u16x4 y;
#pragma unroll
    for (int i = 0; i < 4; i++) y[i] = f2bf((x[i] - mean) * rstd * g[t * 4 + i] + be[t * 4 + i]);
    *(u16x4*)((unsigned short*)outp + ob) = y;
  }
}

// =======================================================================================

extern "C" void kernel_launch(void* const* d_in, const int* in_sizes, int n_in,
                              void* d_out, int out_size, void* d_ws, size_t ws_size,
                              hipStream_t stream) {
  const int M = 16384;
  if (n_in < 43 || in_sizes[0] != 16777216 || in_sizes[25] != 10240 || in_sizes[34] != 4194304) {
    fprintf(stderr, "kernel_launch: unexpected input layout (n_in=%d)\n", n_in);
    return;
  }
  const float* x = (const float*)d_in[0];
  const float* w[3][4]; const float* bia[3][4];
  for (int p = 0; p < 3; p++) {
    w[p][0] = (const float*)d_in[1 + 8 * p + 0]; bia[p][0] = (const float*)d_in[1 + 8 * p + 1];
    w[p][1] = (const float*)d_in[1 + 8 * p + 2]; bia[p][1] = (const float*)d_in[1 + 8 * p + 3];
    w[p][2] = (const float*)d_in[1 + 8 * p + 4]; bia[p][2] = (const float*)d_in[1 + 8 * p + 5];
    w[p][3] = (const float*)d_in[1 + 8 * p + 6]; bia[p][3] = (const float*)d_in[1 + 8 * p + 7];
  }
  const float* cs_key = (const float*)d_in[25];
  const float* ng[4]; const float* nb[4];
  for (int i = 0; i < 4; i++) { ng[i] = (const float*)d_in[26 + 2 * i]; nb[i] = (const float*)d_in[27 + 2 * i]; }
  const float* m_w1[2]; const float* m_b1[2]; const float* m_w2[2]; const float* m_b2[2];
  for (int i = 0; i < 2; i++) {
    m_w1[i] = (const float*)d_in[34 + 4 * i]; m_b1[i] = (const float*)d_in[35 + 4 * i];
    m_w2[i] = (const float*)d_in[36 + 4 * i]; m_b2[i] = (const float*)d_in[37 + 4 * i];
  }

  // ---- workspace ----
  char* base = (char*)d_ws; size_t off = 0;
  auto alloc = [&](size_t bytes) -> void* {
    off = (off + 255) & ~(size_t)255;
    void* p = base + off; off += bytes; return p;
  };
  const size_t W1M = (size_t)1024 * 1024;
  unsigned short* W3ct = (unsigned short*)alloc(3 * W1M * 2);  // [wqT; wkT; wkvT]
  unsigned short* W3hp = (unsigned short*)alloc(3 * W1M * 2);
  unsigned short* Woct = (unsigned short*)alloc(W1M * 2);
  unsigned short* Wohp = (unsigned short*)alloc(W1M * 2);
  unsigned short* Wocs = (unsigned short*)alloc(W1M * 2);
  unsigned short* Wqcs = (unsigned short*)alloc(W1M * 2);
  unsigned short* Wkcs = (unsigned short*)alloc(W1M * 2);
  unsigned short* Wvcs = (unsigned short*)alloc(W1M * 2);
  unsigned short* Wm1u = (unsigned short*)alloc((size_t)4096 * 1024 * 2);
  unsigned short* Wm1d = (unsigned short*)alloc((size_t)1024 * 4096 * 2);
  unsigned short* Wm2u = (unsigned short*)alloc((size_t)4096 * 1024 * 2);
  unsigned short* Wm2d = (unsigned short*)alloc((size_t)1024 * 4096 * 2);
  unsigned short* BtQK = (unsigned short*)alloc((size_t)256 * 1024 * 2);
  float* bqk = (float*)alloc(256 * 4);
  float* b3ct = (float*)alloc(3072 * 4);
  float* b3hp = (float*)alloc(3072 * 4);
  unsigned short* KeyB = (unsigned short*)alloc((size_t)10 * 1024 * 2);
  unsigned short* Kcs = (unsigned short*)alloc((size_t)10 * 1024 * 2);
  unsigned short* Vcs = (unsigned short*)alloc((size_t)10 * 1024 * 2);
  unsigned short* S[6];
  for (int i = 0; i < 6; i++) S[i] = (unsigned short*)alloc((size_t)M * 1024 * 2);
  if (off > ws_size) {
    fprintf(stderr, "kernel_launch: ws too small: need %zu have %zu\n", off, ws_size);
    return;
  }
  // fold scratch aliased into S1 (dead during prep)
  unsigned short* Wvt_ct = S[1];
  unsigned short* Wraw_ct = S[1] + W1M;
  unsigned short* Wvt_hp = S[1] + 2 * W1M;
  unsigned short* Wraw_hp = S[1] + 3 * W1M;

  auto gemm = [&](const unsigned short* Ap, const unsigned short* Bt, const float* bi,
                  unsigned short* Cp, int Mm, int Nn, int Kk, bool gelu, bool bm128) {
    if (bm128) {
      dim3 gg(Nn / 256, Mm / 128);
      if (gelu) k_gemm<128, true><<<gg, 512, 0, stream>>>(Ap, Bt, bi, Cp, Mm, Nn, Kk);
      else      k_gemm<128, false><<<gg, 512, 0, stream>>>(Ap, Bt, bi, Cp, Mm, Nn, Kk);
    } else {
      dim3 gg(Nn / 256, Mm / 256);
      if (gelu) k_gemm<256, true><<<gg, 512, 0, stream>>>(Ap, Bt, bi, Cp, Mm, Nn, Kk);
      else      k_gemm<256, false><<<gg, 512, 0, stream>>>(Ap, Bt, bi, Cp, Mm, Nn, Kk);
    }
  };
  auto tc = [&](const float* src, unsigned short* dst) {
    k_tcast<<<dim3(32, 32), 256, 0, stream>>>(src, dst, 1024, 1024);
  };

  // ---- weight prep ----
  tc(w[0][0], W3ct); tc(w[0][1], W3ct + W1M);
  tc(w[2][0], W3hp); tc(w[2][1], W3hp + W1M);
  tc(w[0][3], Woct); tc(w[2][3], Wohp); tc(w[1][3], Wocs);
  tc(w[1][0], Wqcs); tc(w[1][1], Wkcs); tc(w[1][2], Wvcs);
  k_tcast<<<dim3(128, 32), 256, 0, stream>>>(m_w1[0], Wm1u, 1024, 4096);
  k_tcast<<<dim3(32, 128), 256, 0, stream>>>(m_w2[0], Wm1d, 4096, 1024);
  k_tcast<<<dim3(128, 32), 256, 0, stream>>>(m_w1[1], Wm2u, 1024, 4096);
  k_tcast<<<dim3(32, 128), 256, 0, stream>>>(m_w2[1], Wm2d, 4096, 1024);
  tc(w[0][2], Wvt_ct); k_cast<<<1024, 256, 0, stream>>>(w[0][1], Wraw_ct, 262144);
  tc(w[2][2], Wvt_hp); k_cast<<<1024, 256, 0, stream>>>(w[2][1], Wraw_hp, 262144);
  k_cast<<<16384, 256, 0, stream>>>(x, S[0], 16777216 / 4);
  k_cast<<<10, 256, 0, stream>>>(cs_key, KeyB, 10240 / 4);
  // folded V weights (1024^3)
  k_gemmS<<<dim3(8, 8), 256, 0, stream>>>(Wvt_ct, Wraw_ct, nullptr, W3ct + 2 * W1M, 1024, 1024, 1024);
  k_gemmS<<<dim3(8, 8), 256, 0, stream>>>(Wvt_hp, Wraw_hp, nullptr, W3hp + 2 * W1M, 1024, 1024, 1024);
  // folded biases
  k_cpb<<<4, 256, 0, stream>>>(bia[0][0], bia[0][1], b3ct);
  k_bfold<<<4, 256, 0, stream>>>(bia[0][1], w[0][2], bia[0][2], b3ct + 2048);
  k_cpb<<<4, 256, 0, stream>>>(bia[2][0], bia[2][1], b3hp);
  k_bfold<<<4, 256, 0, stream>>>(bia[2][1], w[2][2], bia[2][2], b3hp + 2048);
  // cs stored patterns + scores fold (correct side of the fold only)
  k_gemm10<<<dim3(10, 16), 256, 0, stream>>>(KeyB, Wkcs, bia[1][1], Kcs);
  k_gemm10<<<dim3(10, 16), 256, 0, stream>>>(Kcs, Wvcs, bia[1][2], Vcs);
  k_wqk<<<256, 256, 0, stream>>>(Wqcs, bia[1][0], Kcs, BtQK, bqk);

  // ---- stage T (L=S=64 attention over seg) ----
  gemm(S[0], W3ct, b3ct, S[1], M, 3072, 1024, false, false);                // QKV -> S1..S3
  k_attn<64, 64, false><<<256 * 16, 256, 0, stream>>>(S[1], S[1] + 1024, S[1] + 2048, S[4], 3072);
  gemm(S[4], Woct, bia[0][3], S[5], M, 1024, 1024, false, true);            // enc -> S5
  k_ln<0, false><<<M, 256, 0, stream>>>(S[0], S[5], ng[0], nb[0], S[1]);    // D -> S1
  gemm(S[1], Wm1u, m_b1[0], S[2], M, 4096, 1024, true, false);              // H -> S2..S5
  gemm(S[2], Wm1d, m_b2[0], S[0], M, 1024, 4096, false, true);              // R -> S0
  k_ln<1, false><<<M, 256, 0, stream>>>(S[1], S[0], ng[1], nb[1], S[2]);    // S_in -> S2 (permuted)

  // ---- stage S (L=32) ----
  gemm(S[2], W3hp, b3hp, S[3], M, 3072, 1024, false, false);                // QKVhp -> S3..S5
  k_attn<32, 32, false><<<512 * 16, 256, 0, stream>>>(S[3], S[3] + 1024, S[3] + 2048, S[0], 3072);
  gemm(S[0], Wohp, bia[2][3], S[1], M, 1024, 1024, false, true);            // PH -> S1
  // cs-Hopfield: folded scores -> entmax10 -> PV in MIX layout -> out-proj
  k_gemmS<<<dim3(2, 128), 256, 0, stream>>>(S[2], BtQK, bqk, S[0], M, 256, 1024);   // SC -> S0[0:8M]
  k_entmax10<<<M / 16, 256, 0, stream>>>(S[0], S[0] + (size_t)M * 256);             // A -> S0[8M:16M]
  k_pvmix<<<M, 256, 0, stream>>>(S[0] + (size_t)M * 256, Vcs, S[3]);                // mix -> S3
  gemm(S[3], Wocs, bia[1][3], S[4], M, 1024, 1024, false, true);            // SH -> S4
  k_ln<0, false><<<M, 256, 0, stream>>>(S[4], S[1], ng[2], nb[2], S[0]);    // DE -> S0
  gemm(S[0], Wm2u, m_b1[1], S[1], M, 4096, 1024, true, false);              // H -> S1..S4
  gemm(S[1], Wm2d, m_b2[1], S[5], M, 1024, 4096, false, true);              // R2 -> S5
  k_ln<2, true><<<M, 256, 0, stream>>>(S[0], S[5], ng[3], nb[3], d_out);    // final LN+permute f32
}

// Round 14
// 1617.131 us; speedup vs baseline: 2.6768x; 2.6768x over previous
//
#include <hip/hip_runtime.h>
#include <cstdio>

typedef __bf16 bf16x8 __attribute__((ext_vector_type(8)));
typedef float f32x4 __attribute__((ext_vector_type(4)));
typedef int i32x4 __attribute__((ext_vector_type(4)));
typedef unsigned short u16x4 __attribute__((ext_vector_type(4)));

__device__ __forceinline__ float bf2f(unsigned short u) {
  union { unsigned int i; float f; } x; x.i = ((unsigned int)u) << 16; return x.f;
}
__device__ __forceinline__ unsigned short f2bf(float f) {
  union { float f; unsigned int i; } x; x.f = f;
  unsigned int r = x.i + 0x7fffu + ((x.i >> 16) & 1u);
  return (unsigned short)(r >> 16);
}

// async global->LDS, 16B per lane; LDS dest is wave-uniform base + lane*16
__device__ __forceinline__ void gl2lds16(const unsigned short* g, unsigned short* l) {
  __builtin_amdgcn_global_load_lds((const __attribute__((address_space(1))) unsigned int*)g,
                                   (__attribute__((address_space(3))) unsigned int*)l, 16, 0, 0);
}

// ---------------- elementwise f32 -> bf16 cast (vec4) ----------------
__global__ __launch_bounds__(256) void k_cast(const float* __restrict__ in,
                                              unsigned short* __restrict__ out, int n4) {
  int i = blockIdx.x * 256 + threadIdx.x;
  if (i >= n4) return;
  f32x4 v = ((const f32x4*)in)[i];
  u16x4 o;
  o[0] = f2bf(v[0]); o[1] = f2bf(v[1]); o[2] = f2bf(v[2]); o[3] = f2bf(v[3]);
  ((u16x4*)out)[i] = o;
}

// -------- transpose-cast: src f32 [K][N] -> dst bf16 [N][K] --------
__global__ __launch_bounds__(256) void k_tcast(const float* __restrict__ src,
                                               unsigned short* __restrict__ dst,
                                               int K, int N) {
  __shared__ float tile[32][33];
  int gx = blockIdx.x * 32;  // N dim
  int gy = blockIdx.y * 32;  // K dim
  int t = threadIdx.x;
  int c = t & 31, r0 = t >> 5;
#pragma unroll
  for (int i = 0; i < 4; i++) {
    int r = r0 + i * 8;
    tile[r][c] = src[(size_t)(gy + r) * N + gx + c];
  }
  __syncthreads();
#pragma unroll
  for (int i = 0; i < 4; i++) {
    int r = r0 + i * 8;
    dst[(size_t)(gx + r) * K + gy + c] = f2bf(tile[c][r]);
  }
}

// ---- folded bias: out[n] = bv[n] + sum_j bk[j]*wv[j][n]  (f32, 1024 wide) ----
__global__ __launch_bounds__(256) void k_bfold(const float* __restrict__ bk,
                                               const float* __restrict__ wv,
                                               const float* __restrict__ bv,
                                               float* __restrict__ out) {
  int n = blockIdx.x * 256 + threadIdx.x;
  float acc = bv[n];
#pragma unroll 8
  for (int j = 0; j < 1024; j++) acc += bk[j] * wv[(size_t)j * 1024 + n];
  out[n] = acc;
}

// ---- concat two 1024-f32 vectors into out[0..2047] ----
__global__ __launch_bounds__(256) void k_cpb(const float* __restrict__ a,
                                             const float* __restrict__ b,
                                             float* __restrict__ out) {
  int t = blockIdx.x * 256 + threadIdx.x;
  out[t] = a[t];
  out[1024 + t] = b[t];
}

// ---- cs-fold: BtQK[n=(h*16+s)][k] = sum_e wqT[h*64+e][k]*K[s][h*64+e]; bqk[n]=bq.K ----
__global__ __launch_bounds__(256) void k_wqk(const unsigned short* __restrict__ wqT,
                                             const float* __restrict__ bq,
                                             const unsigned short* __restrict__ Kcs,
                                             unsigned short* __restrict__ BtQK,
                                             float* __restrict__ bqk) {
  int n = blockIdx.x, h = n >> 4, s = n & 15, t = threadIdx.x;
  if (s >= 10) {
    ((u16x4*)(BtQK + (size_t)n * 1024))[t] = u16x4{0, 0, 0, 0};
    if (t == 0) bqk[n] = 0.f;
    return;
  }
  float acc[4] = {0.f, 0.f, 0.f, 0.f};
  for (int e = 0; e < 64; e++) {
    float kv = bf2f(Kcs[s * 1024 + h * 64 + e]);
    u16x4 rv = ((const u16x4*)(wqT + (size_t)(h * 64 + e) * 1024))[t];
#pragma unroll
    for (int i = 0; i < 4; i++) acc[i] += bf2f(rv[i]) * kv;
  }
  u16x4 o;
#pragma unroll
  for (int i = 0; i < 4; i++) o[i] = f2bf(acc[i]);
  ((u16x4*)(BtQK + (size_t)n * 1024))[t] = o;
  if (t == 0) {
    float b = 0.f;
    for (int e = 0; e < 64; e++) b += bq[h * 64 + e] * bf2f(Kcs[s * 1024 + h * 64 + e]);
    bqk[n] = b;
  }
}

// ---- entmax-1.5 over 10 stored patterns, fully in registers (thread = (row,head)) ----
__global__ __launch_bounds__(256) void k_entmax10(const unsigned short* __restrict__ SC,
                                                  unsigned short* __restrict__ A) {
  int t = threadIdx.x;
  int m = blockIdx.x * 16 + (t >> 4), h = t & 15;
  const unsigned short* p = SC + (size_t)m * 256 + h * 16;
  float xs[10], mx = -1e30f;
#pragma unroll
  for (int s = 0; s < 10; s++) { xs[s] = bf2f(p[s]) * 0.0625f; mx = fmaxf(mx, xs[s]); }
  float lo = mx - 1.f, hi = mx - 0.31622776601683794f;  // d^-0.5, d=10
#pragma unroll 1
  for (int it = 0; it < 26; it++) {
    float mid = 0.5f * (lo + hi);
    float f = 0.f;
#pragma unroll
    for (int s = 0; s < 10; s++) { float dd = fmaxf(xs[s] - mid, 0.f); f += dd * dd; }
    bool gt = f > 1.f;
    lo = gt ? mid : lo;
    hi = gt ? hi : mid;
  }
  float tau = 0.5f * (lo + hi), ps = 0.f;
#pragma unroll
  for (int s = 0; s < 10; s++) { float dd = fmaxf(xs[s] - tau, 0.f); xs[s] = dd * dd; ps += xs[s]; }
  float r = 1.f / ps;
  unsigned short* q = A + (size_t)m * 256 + h * 16;
  u16x4 o0, o1, o2, o3;
#pragma unroll
  for (int i = 0; i < 4; i++) o0[i] = f2bf(xs[i] * r);
#pragma unroll
  for (int i = 0; i < 4; i++) o1[i] = f2bf(xs[4 + i] * r);
  o2[0] = f2bf(xs[8] * r); o2[1] = f2bf(xs[9] * r); o2[2] = 0; o2[3] = 0;
  o3[0] = o3[1] = o3[2] = o3[3] = 0;
  ((u16x4*)q)[0] = o0; ((u16x4*)q)[1] = o1; ((u16x4*)q)[2] = o2; ((u16x4*)q)[3] = o3;
}

// ---- PV + Hopfield "mix": out_mix[(b*32+ln)][c] = sum_s A[b,h,l,s] * V[s][h*64+d]
// with h = ln>>1, l = (ln&1)*16 + (c>>6), d = c&63.  One block per output row.
__global__ __launch_bounds__(256) void k_pvmix(const unsigned short* __restrict__ A,
                                               const unsigned short* __restrict__ Vcs,
                                               unsigned short* __restrict__ Out) {
  __shared__ float Vs[10][64];
  __shared__ float Asm[16][10];
  const int row = blockIdx.x;
  const int b = row >> 5, ln = row & 31;
  const int h = ln >> 1, lbase = (ln & 1) * 16;
  const int t = threadIdx.x;
  if (t < 160) {
    int j = t / 10, s = t - j * 10;
    Asm[j][s] = bf2f(A[((size_t)(b * 32 + lbase + j)) * 256 + h * 16 + s]);
  }
  for (int idx = t; idx < 640; idx += 256) {
    int s = idx >> 6, d = idx & 63;
    Vs[s][d] = bf2f(Vcs[s * 1024 + h * 64 + d]);
  }
  __syncthreads();
  const int j = t >> 4, d0 = (t & 15) * 4;
  float acc[4] = {0.f, 0.f, 0.f, 0.f};
#pragma unroll
  for (int s = 0; s < 10; s++) {
    float a = Asm[j][s];
#pragma unroll
    for (int i = 0; i < 4; i++) acc[i] += a * Vs[s][d0 + i];
  }
  u16x4 o;
#pragma unroll
  for (int i = 0; i < 4; i++) o[i] = f2bf(acc[i]);
  ((u16x4*)(Out + (size_t)row * 1024))[t] = o;
}

// ======== r11-proven 8-phase-family GEMM: 256x256, BK=64 (for N%256 big GEMMs) ========
template <bool GELU>
__global__ __launch_bounds__(512, 2) void k_gemm8(const unsigned short* __restrict__ A,
                                                  const unsigned short* __restrict__ Bt,
                                                  const float* __restrict__ bias,
                                                  unsigned short* __restrict__ C,
                                                  int M, int N, int K) {
  __shared__ unsigned short As[2][256 * 64];
  __shared__ unsigned short Bs[2][256 * 64];
  const int rowA0 = blockIdx.y * 256, colB0 = blockIdx.x * 256;
  const int t = threadIdx.x, w = t >> 6, lane = t & 63;
  const int wm = w >> 2, wn = w & 3;
  const int g = lane >> 4, ra = lane & 15;
  const int koff0 = (((0 * 4 + g) ^ (ra & 7)) * 8);
  const int koff1 = (((1 * 4 + g) ^ (ra & 7)) * 8);
  const int srow = w * 8 + (lane >> 3);
  const int schunk = ((lane & 7) ^ ((lane >> 3) & 7)) * 8;

  f32x4 acc[8][4] = {};

  auto stageA = [&](int buf, int kk) {
#pragma unroll
    for (int gq = 0; gq < 4; gq++)
      gl2lds16(A + (size_t)(rowA0 + gq * 64 + srow) * K + kk + schunk,
               &As[buf][gq * 4096 + w * 512]);
  };
  auto stageB = [&](int buf, int kk) {
#pragma unroll
    for (int gq = 0; gq < 4; gq++)
      gl2lds16(Bt + (size_t)(colB0 + gq * 64 + srow) * K + kk + schunk,
               &Bs[buf][gq * 4096 + w * 512]);
  };

  const int NT = K >> 6;
  stageA(0, 0); stageB(0, 0);
  if (NT > 1) { stageA(1, 64); stageB(1, 64); }
  if (NT > 1) asm volatile("s_waitcnt vmcnt(8)" ::: "memory");
  else        asm volatile("s_waitcnt vmcnt(0)" ::: "memory");
  __builtin_amdgcn_sched_barrier(0);
  __builtin_amdgcn_s_barrier();

  bf16x8 aH[4][2], bH[2][2][2];
  const int arow0 = wm * 128, brow0 = wn * 64;
  for (int j = 0; j < NT; ++j) {
    const int buf = j & 1;
    const unsigned short* Ab = &As[buf][0];
    const unsigned short* Bb = &Bs[buf][0];
    // phase 0
#pragma unroll
    for (int fr = 0; fr < 4; fr++) {
      aH[fr][0] = *(const bf16x8*)&Ab[(arow0 + fr * 16 + ra) * 64 + koff0];
      aH[fr][1] = *(const bf16x8*)&Ab[(arow0 + fr * 16 + ra) * 64 + koff1];
    }
#pragma unroll
    for (int fc = 0; fc < 2; fc++) {
      bH[0][fc][0] = *(const bf16x8*)&Bb[(brow0 + fc * 16 + ra) * 64 + koff0];
      bH[0][fc][1] = *(const bf16x8*)&Bb[(brow0 + fc * 16 + ra) * 64 + koff1];
    }
    __builtin_amdgcn_sched_barrier(0);
    __builtin_amdgcn_s_barrier();
    __builtin_amdgcn_sched_barrier(0);
    __builtin_amdgcn_s_setprio(1);
#pragma unroll
    for (int fr = 0; fr < 4; fr++)
#pragma unroll
      for (int fc = 0; fc < 2; fc++)
#pragma unroll
        for (int ks = 0; ks < 2; ks++)
          acc[fr][fc] = __builtin_amdgcn_mfma_f32_16x16x32_bf16(aH[fr][ks], bH[0][fc][ks], acc[fr][fc], 0, 0, 0);
    __builtin_amdgcn_s_setprio(0);
    __builtin_amdgcn_sched_barrier(0);
    __builtin_amdgcn_s_barrier();
    // phase 1
#pragma unroll
    for (int fc = 0; fc < 2; fc++) {
      bH[1][fc][0] = *(const bf16x8*)&Bb[(brow0 + 32 + fc * 16 + ra) * 64 + koff0];
      bH[1][fc][1] = *(const bf16x8*)&Bb[(brow0 + 32 + fc * 16 + ra) * 64 + koff1];
    }
    __builtin_amdgcn_sched_barrier(0);
    __builtin_amdgcn_s_barrier();
    __builtin_amdgcn_sched_barrier(0);
    __builtin_amdgcn_s_setprio(1);
#pragma unroll
    for (int fr = 0; fr < 4; fr++)
#pragma unroll
      for (int fc = 0; fc < 2; fc++)
#pragma unroll
        for (int ks = 0; ks < 2; ks++)
          acc[fr][2 + fc] = __builtin_amdgcn_mfma_f32_16x16x32_bf16(aH[fr][ks], bH[1][fc][ks], acc[fr][2 + fc], 0, 0, 0);
    __builtin_amdgcn_s_setprio(0);
    __builtin_amdgcn_sched_barrier(0);
    __builtin_amdgcn_s_barrier();
    // phase 2: stage B(j+2) into same buf (B(j) reads done)
#pragma unroll
    for (int fr = 0; fr < 4; fr++) {
      aH[fr][0] = *(const bf16x8*)&Ab[(arow0 + 64 + fr * 16 + ra) * 64 + koff0];
      aH[fr][1] = *(const bf16x8*)&Ab[(arow0 + 64 + fr * 16 + ra) * 64 + koff1];
    }
    if (j + 2 < NT) stageB(buf, (j + 2) << 6);
    __builtin_amdgcn_sched_barrier(0);
    __builtin_amdgcn_s_barrier();
    __builtin_amdgcn_sched_barrier(0);
    __builtin_amdgcn_s_setprio(1);
#pragma unroll
    for (int fr = 0; fr < 4; fr++)
#pragma unroll
      for (int fc = 0; fc < 2; fc++)
#pragma unroll
        for (int ks = 0; ks < 2; ks++)
          acc[4 + fr][fc] = __builtin_amdgcn_mfma_f32_16x16x32_bf16(aH[fr][ks], bH[0][fc][ks], acc[4 + fr][fc], 0, 0, 0);
    __builtin_amdgcn_s_setprio(0);
    __builtin_amdgcn_sched_barrier(0);
    __builtin_amdgcn_s_barrier();
    // phase 3: stage A(j+2); counted boundary
    if (j + 2 < NT) stageA(buf, (j + 2) << 6);
    __builtin_amdgcn_sched_barrier(0);
    __builtin_amdgcn_s_setprio(1);
#pragma unroll
    for (int fr = 0; fr < 4; fr++)
#pragma unroll
      for (int fc = 0; fc < 2; fc++)
#pragma unroll
        for (int ks = 0; ks < 2; ks++)
          acc[4 + fr][2 + fc] = __builtin_amdgcn_mfma_f32_16x16x32_bf16(aH[fr][ks], bH[1][fc][ks], acc[4 + fr][2 + fc], 0, 0, 0);
    __builtin_amdgcn_s_setprio(0);
    if (j + 1 < NT) {
      if (j + 2 < NT) asm volatile("s_waitcnt vmcnt(8)" ::: "memory");
      else            asm volatile("s_waitcnt vmcnt(0)" ::: "memory");
    }
    __builtin_amdgcn_sched_barrier(0);
    __builtin_amdgcn_s_barrier();
  }
  asm volatile("s_waitcnt vmcnt(0) lgkmcnt(0)" ::: "memory");
  __builtin_amdgcn_s_barrier();

  unsigned short* Ep = &As[0][0] + w * 1024;
  const int grow0 = rowA0 + wm * 128;
  const int gcol0 = colB0 + wn * 64;
  float bv[4];
#pragma unroll
  for (int n = 0; n < 4; n++) bv[n] = bias ? bias[gcol0 + n * 16 + ra] : 0.f;
  const int rdrow = lane >> 3, rg = lane & 7;
#pragma unroll
  for (int m = 0; m < 8; m++) {
#pragma unroll
    for (int n = 0; n < 4; n++)
#pragma unroll
      for (int i = 0; i < 4; i++) {
        int r = g * 4 + i;
        float v = acc[m][n][i] + bv[n];
        if (GELU) v = 0.5f * v * (1.f + erff(v * 0.70710678118654752f));
        Ep[r * 64 + ((ra + n * 16) ^ ((r & 7) << 3))] = f2bf(v);
      }
    asm volatile("s_waitcnt lgkmcnt(0)" ::: "memory");
    __builtin_amdgcn_sched_barrier(0);
#pragma unroll
    for (int p = 0; p < 2; p++) {
      int rr = p * 8 + rdrow;
      bf16x8 val = *(const bf16x8*)&Ep[rr * 64 + ((rg ^ (rr & 7)) << 3)];
      *(bf16x8*)&C[(size_t)(grow0 + m * 16 + rr) * N + gcol0 + rg * 8] = val;
    }
    asm volatile("s_waitcnt lgkmcnt(0)" ::: "memory");
  }
}

// ======== 2-buffer GEMM, BM=128 x 256, BK=32 (r13-verified-correct; bounds relaxed) ========
// 48 KB LDS + ~105 VGPR -> target 2 blocks/CU (the occupancy experiment, spill-free).
template <bool GELU>
__global__ __launch_bounds__(512) void k_gemmN(const unsigned short* __restrict__ A,
                                               const unsigned short* __restrict__ Bt,
                                               const float* __restrict__ bias,
                                               unsigned short* __restrict__ C,
                                               int M, int N, int K) {
  constexpr int BM = 128, RPW = 64, RF = 4;
  __shared__ unsigned short As[2][BM * 32];
  __shared__ unsigned short Bs[2][256 * 32];
  const int rowA0 = blockIdx.y * BM, colB0 = blockIdx.x * 256;
  const int t = threadIdx.x, w = t >> 6, lane = t & 63;
  const int wm = w >> 2, wn = w & 3;
  const int g = lane >> 4, ra = lane & 15;
  const int gp8 = (g ^ ((ra >> 1) & 3)) * 8;
  const int srow = lane >> 2;
  const int schunk = ((lane & 3) ^ ((lane >> 3) & 3)) * 8;

  f32x4 acc[RF][4] = {};

  auto stage = [&](int buf, int kk) {
    gl2lds16(A + (size_t)(rowA0 + w * 16 + srow) * K + kk + schunk, &As[buf][w * 512]);
#pragma unroll
    for (int i = 0; i < 2; i++)
      gl2lds16(Bt + (size_t)(colB0 + w * 16 + i * 128 + srow) * K + kk + schunk,
               &Bs[buf][(w * 16 + i * 128) * 32]);
  };

  const int NT = K >> 5;
  stage(0, 0);
  int buf = 0;
  for (int j = 0; j < NT; ++j) {
    asm volatile("s_waitcnt vmcnt(0)" ::: "memory");
    __syncthreads();
    if (j + 1 < NT) stage(buf ^ 1, (j + 1) * 32);
    const unsigned short* Ab = &As[buf][0];
    const unsigned short* Bb = &Bs[buf][0];
    bf16x8 bfr[4];
#pragma unroll
    for (int fc = 0; fc < 4; fc++)
      bfr[fc] = *(const bf16x8*)&Bb[(wn * 64 + fc * 16 + ra) * 32 + gp8];
#pragma unroll
    for (int fr = 0; fr < RF; fr++) {
      bf16x8 af = *(const bf16x8*)&Ab[(wm * RPW + fr * 16 + ra) * 32 + gp8];
#pragma unroll
      for (int fc = 0; fc < 4; fc++)
        acc[fr][fc] = __builtin_amdgcn_mfma_f32_16x16x32_bf16(af, bfr[fc], acc[fr][fc], 0, 0, 0);
    }
    buf ^= 1;
  }
  __syncthreads();

  unsigned short* Ep = &As[0][0] + w * 1024;
  const int grow0 = rowA0 + wm * RPW;
  const int gcol0 = colB0 + wn * 64;
  float bv[4];
#pragma unroll
  for (int n = 0; n < 4; n++) bv[n] = bias ? bias[gcol0 + n * 16 + ra] : 0.f;
  const int rdrow = lane >> 3, rg = lane & 7;
#pragma unroll
  for (int m = 0; m < RF; m++) {
#pragma unroll
    for (int n = 0; n < 4; n++)
#pragma unroll
      for (int i = 0; i < 4; i++) {
        int r = g * 4 + i;
        float v = acc[m][n][i] + bv[n];
        if (GELU) v = 0.5f * v * (1.f + erff(v * 0.70710678118654752f));
        Ep[r * 64 + ((ra + n * 16) ^ ((r & 7) << 3))] = f2bf(v);
      }
    asm volatile("s_waitcnt lgkmcnt(0)" ::: "memory");
    __builtin_amdgcn_sched_barrier(0);
#pragma unroll
    for (int p = 0; p < 2; p++) {
      int rr = p * 8 + rdrow;
      bf16x8 val = *(const bf16x8*)&Ep[rr * 64 + ((rg ^ (rr & 7)) << 3)];
      *(bf16x8*)&C[(size_t)(grow0 + m * 16 + rr) * N + gcol0 + rg * 8] = val;
    }
    asm volatile("s_waitcnt lgkmcnt(0)" ::: "memory");
  }
}

// ======== small MFMA GEMM (folds + skinny cs GEMMs): 128^2 tile, ring-3 ========
__global__ __launch_bounds__(256) void k_gemmS(const unsigned short* __restrict__ A,
                                               const unsigned short* __restrict__ Bt,
                                               const float* __restrict__ bias,
                                               unsigned short* __restrict__ C,
                                               int M, int N, int K) {
  __shared__ unsigned short As[3][128 * 32];
  __shared__ unsigned short Bs[3][128 * 32];
  const int rowA0 = blockIdx.y * 128, colB0 = blockIdx.x * 128;
  const int t = threadIdx.x, w = t >> 6, lane = t & 63;
  const int wr = w >> 1, wc = w & 1;
  const int srow = w * 16 + (lane >> 2);
  const int schunk = (lane & 3) ^ ((lane >> 3) & 3);
  const unsigned short* pa = A + (size_t)(rowA0 + srow) * K + schunk * 8;
  const unsigned short* pb = Bt + (size_t)(colB0 + srow) * K + schunk * 8;
  const size_t row64 = (size_t)64 * K;
  f32x4 acc[4][4] = {};
  const int g = lane >> 4, ra = lane & 15;
  const int gp8 = (g ^ ((ra >> 1) & 3)) * 8;
  auto stage = [&](int buf, int kk) {
    gl2lds16(pa + kk, &As[buf][w * 512]);
    gl2lds16(pa + row64 + kk, &As[buf][2048 + w * 512]);
    gl2lds16(pb + kk, &Bs[buf][w * 512]);
    gl2lds16(pb + row64 + kk, &Bs[buf][2048 + w * 512]);
  };
  const int NT = K >> 5;
  stage(0, 0);
  if (NT > 1) stage(1, 32);
  int cur = 0;
  for (int j = 0; j < NT; ++j) {
    if (j + 1 < NT) asm volatile("s_waitcnt vmcnt(4)" ::: "memory");
    else            asm volatile("s_waitcnt vmcnt(0)" ::: "memory");
    __syncthreads();
    if (j + 2 < NT) { int nb = cur + 2; if (nb >= 3) nb -= 3; stage(nb, (j + 2) * 32); }
    bf16x8 af[4], bfr[4];
#pragma unroll
    for (int m = 0; m < 4; m++)
      af[m] = *(const bf16x8*)&As[cur][(wr * 64 + m * 16 + ra) * 32 + gp8];
#pragma unroll
    for (int n = 0; n < 4; n++)
      bfr[n] = *(const bf16x8*)&Bs[cur][(wc * 64 + n * 16 + ra) * 32 + gp8];
#pragma unroll
    for (int m = 0; m < 4; m++)
#pragma unroll
      for (int n = 0; n < 4; n++)
        acc[m][n] = __builtin_amdgcn_mfma_f32_16x16x32_bf16(af[m], bfr[n], acc[m][n], 0, 0, 0);
    __syncthreads();
    cur += 1; if (cur >= 3) cur -= 3;
  }
  const int cr = g * 4, cc = ra;
#pragma unroll
  for (int m = 0; m < 4; m++) {
    int grow = rowA0 + wr * 64 + m * 16 + cr;
#pragma unroll
    for (int n = 0; n < 4; n++) {
      int gcol = colB0 + wc * 64 + n * 16 + cc;
      float bvv = bias ? bias[gcol] : 0.f;
#pragma unroll
      for (int i = 0; i < 4; i++)
        C[(size_t)(grow + i) * N + gcol] = f2bf(acc[m][n][i] + bvv);
    }
  }
}

// ---------------- small GEMM (M<=10): C[Mr][1024] = A[Mr][1024] * Wt^T + bias ----------------
__global__ __launch_bounds__(256) void k_gemm10(const unsigned short* __restrict__ A,
                                                const unsigned short* __restrict__ Bt,
                                                const float* __restrict__ bias,
                                                unsigned short* __restrict__ C) {
  __shared__ float af[1024];
  int m = blockIdx.x, nb = blockIdx.y;
  int t = threadIdx.x;
#pragma unroll
  for (int i = 0; i < 4; i++) af[t * 4 + i] = bf2f(A[(size_t)m * 1024 + t * 4 + i]);
  __syncthreads();
  int w = t >> 6, lane = t & 63;
  for (int n = nb * 64 + w; n < nb * 64 + 64; n += 4) {
    const unsigned short* brow = Bt + (size_t)n * 1024 + lane * 16;
    float acc = 0.f;
#pragma unroll
    for (int j = 0; j < 16; j++) acc += af[lane * 16 + j] * bf2f(brow[j]);
#pragma unroll
    for (int o = 32; o; o >>= 1) acc += __shfl_xor(acc, o);
    if (lane == 0) C[(size_t)m * 1024 + n] = f2bf(acc + bias[n]);
  }
}

// ---------------- entmax-1.5 attention, MFMA version (RS = input row stride) ----------------
template <int L, int S, bool SHARED>
__global__ __launch_bounds__(256) void k_attn(const unsigned short* __restrict__ Q,
                                              const unsigned short* __restrict__ Kb,
                                              const unsigned short* __restrict__ Vb,
                                              unsigned short* __restrict__ Out, int RS) {
  constexpr int SP = (S <= 32) ? 32 : 64;
  constexpr int QST = 72;
  constexpr int VST = SP + 8;
  constexpr int CST = SP + 4;
  __shared__ unsigned short Qs[L * QST];
  __shared__ unsigned short Ks[SP * QST];
  __shared__ unsigned short Vt[64 * VST];
  __shared__ float Sc[L * CST];
  __shared__ float Rps[L];
  const int blk = blockIdx.x, batch = blk >> 4, h = blk & 15;
  const int t = threadIdx.x, w = t >> 6, lane = t & 63;
  for (int c = t; c < L * 8; c += 256) {
    int r = c >> 3, ch = (c & 7) * 8;
    *(i32x4*)&Qs[r * QST + ch] =
        *(const i32x4*)&Q[((size_t)(batch * L + r)) * RS + h * 64 + ch];
  }
  for (int c = t; c < SP * 8; c += 256) {
    int r = c >> 3, ch = (c & 7) * 8;
    i32x4 v = {0, 0, 0, 0};
    if (r < S) {
      size_t rb = SHARED ? (size_t)r : (size_t)(batch * S + r);
      v = *(const i32x4*)&Kb[rb * RS + h * 64 + ch];
    }
    *(i32x4*)&Ks[r * QST + ch] = v;
  }
  for (int c = t; c < SP * 64; c += 256) {
    int s = c >> 6, e = c & 63;
    unsigned short v = 0;
    if (s < S) {
      size_t rb = SHARED ? (size_t)s : (size_t)(batch * S + s);
      v = Vb[rb * RS + h * 64 + e];
    }
    Vt[e * VST + s] = v;
  }
  __syncthreads();
  const int ka = (lane >> 4) * 8, ra = lane & 15;
  const int cr = (lane >> 4) * 4, cc = lane & 15;
  constexpr int NT = SP / 16, TT = (L / 16) * NT;
  for (int tt = w; tt < TT; tt += 4) {
    int m = tt / NT, n = tt % NT;
    f32x4 a = {0.f, 0.f, 0.f, 0.f};
#pragma unroll
    for (int ks = 0; ks < 2; ks++) {
      bf16x8 af = *(const bf16x8*)&Qs[(m * 16 + ra) * QST + ks * 32 + ka];
      bf16x8 bf = *(const bf16x8*)&Ks[(n * 16 + ra) * QST + ks * 32 + ka];
      a = __builtin_amdgcn_mfma_f32_16x16x32_bf16(af, bf, a, 0, 0, 0);
    }
#pragma unroll
    for (int i = 0; i < 4; i++)
      Sc[(m * 16 + cr + i) * CST + n * 16 + cc] = a[i] * 0.0625f;
  }
  __syncthreads();
  constexpr int G = 256 / L, RW = 64 / G, SL = SP / G;
  const int row = w * RW + lane / G, sub = lane % G;
  float xs[SL];
#pragma unroll
  for (int j = 0; j < SL; j++) {
    int s = sub * SL + j;
    float v = Sc[row * CST + s];
    if (S < SP && s >= S) v = -1e30f;
    xs[j] = v;
  }
  float mx = xs[0];
#pragma unroll
  for (int j = 1; j < SL; j++) mx = fmaxf(mx, xs[j]);
#pragma unroll
  for (int o = G / 2; o; o >>= 1) mx = fmaxf(mx, __shfl_xor(mx, o));
  const float hoff = (S == 64) ? 0.125f : (S == 32) ? 0.17677669529663687f : 0.31622776601683794f;
  float lo = mx - 1.f, hi = mx - hoff;
#pragma unroll 1
  for (int it = 0; it < 26; it++) {
    float mid = 0.5f * (lo + hi);
    float f = 0.f;
#pragma unroll
    for (int j = 0; j < SL; j++) { float dd = fmaxf(xs[j] - mid, 0.f); f += dd * dd; }
#pragma unroll
    for (int o = G / 2; o; o >>= 1) f += __shfl_xor(f, o);
    bool gt = f > 1.f;
    lo = gt ? mid : lo;
    hi = gt ? hi : mid;
  }
  float tau = 0.5f * (lo + hi);
  float ps = 0.f;
#pragma unroll
  for (int j = 0; j < SL; j++) { float dd = fmaxf(xs[j] - tau, 0.f); xs[j] = dd * dd; ps += xs[j]; }
#pragma unroll
  for (int o = G / 2; o; o >>= 1) ps += __shfl_xor(ps, o);
  if (sub == 0) Rps[row] = 1.f / ps;
  unsigned short* Pb = Qs;
#pragma unroll
  for (int j = 0; j < SL; j += 4) {
    u16x4 pv;
#pragma unroll
    for (int jj = 0; jj < 4; jj++) pv[jj] = f2bf(xs[j + jj]);
    *(u16x4*)&Pb[row * VST + sub * SL + j] = pv;
  }
  __syncthreads();
  constexpr int TT2 = (L / 16) * 4;
  for (int tt = w; tt < TT2; tt += 4) {
    int m = tt >> 2, n = tt & 3;
    f32x4 a = {0.f, 0.f, 0.f, 0.f};
#pragma unroll
    for (int ks = 0; ks < SP / 32; ks++) {
      bf16x8 af = *(const bf16x8*)&Pb[(m * 16 + ra) * VST + ks * 32 + ka];
      bf16x8 bf = *(const bf16x8*)&Vt[(n * 16 + ra) * VST + ks * 32 + ka];
      a = __builtin_amdgcn_mfma_f32_16x16x32_bf16(af, bf, a, 0, 0, 0);
    }
#pragma unroll
    for (int i = 0; i < 4; i++) {
      int l = m * 16 + cr + i, e = n * 16 + cc;
      float val = a[i] * Rps[l];
      int l_new = h * (L / 16) + (l >> 4);
      int cg = (l & 15) * 64 + e;
      Out[((size_t)(batch * L + l_new)) * 1024 + cg] = f2bf(val);
    }
  }
}

// ---------------- LayerNorm(a+b) * g + be, optional row permutation / f32 out ----------------
template <int MODE, bool F32OUT>
__global__ __launch_bounds__(256) void k_ln(const unsigned short* __restrict__ a,
                                            const unsigned short* __restrict__ b,
                                            const float* __restrict__ g,
                                            const float* __restrict__ be,
                                            void* __restrict__ outp) {
  __shared__ float red[8];
  int r = blockIdx.x, t = threadIdx.x;
  size_t base = (size_t)r * 1024 + t * 4;
  u16x4 av = *(const u16x4*)(a + base);
  u16x4 bv = *(const u16x4*)(b + base);
  float x[4];
  float s = 0.f, ss = 0.f;
#pragma unroll
  for (int i = 0; i < 4; i++) {
    x[i] = bf2f(av[i]) + bf2f(bv[i]);
    s += x[i]; ss += x[i] * x[i];
  }
#pragma unroll
  for (int o = 32; o; o >>= 1) { s += __shfl_xor(s, o); ss += __shfl_xor(ss, o); }
  int w = t >> 6;
  if ((t & 63) == 0) { red[w] = s; red[4 + w] = ss; }
  __syncthreads();
  s = red[0] + red[1] + red[2] + red[3];
  ss = red[4] + red[5] + red[6] + red[7];
  float mean = s * (1.f / 1024.f);
  float var = ss * (1.f / 1024.f) - mean * mean;
  float rstd = rsqrtf(var + 1e-5f);
  int orow;
  if (MODE == 0) orow = r;
  else if (MODE == 1) { int bi = r >> 11, rem = r & 2047; int tt = rem >> 6, sd = rem & 63; orow = (bi << 11) + sd * 32 + tt; }
  else { int bi = r >> 11, rem = r & 2047; int sd = rem >> 5, tt = rem & 31; orow = (bi << 11) + tt * 64 + sd; }
  size_t ob = (size_t)orow * 1024 + t * 4;
  if (F32OUT) {
    f32x4 y;
#pragma unroll
    for (int i = 0; i < 4; i++) y[i] = (x[i] - mean) * rstd * g[t * 4 + i] + be[t * 4 + i];
    *(f32x4*)((float*)outp + ob) = y;
  } else {
    u16x4 y;
#pragma unroll
    for (int i = 0; i < 4; i++) y[i] = f2bf((x[i] - mean) * rstd * g[t * 4 + i] + be[t * 4 + i]);
    *(u16x4*)((unsigned short*)outp + ob) = y;
  }
}

// =======================================================================================

extern "C" void kernel_launch(void* const* d_in, const int* in_sizes, int n_in,
                              void* d_out, int out_size, void* d_ws, size_t ws_size,
                              hipStream_t stream) {
  const int M = 16384;
  if (n_in < 43 || in_sizes[0] != 16777216 || in_sizes[25] != 10240 || in_sizes[34] != 4194304) {
    fprintf(stderr, "kernel_launch: unexpected input layout (n_in=%d)\n", n_in);
    return;
  }
  const float* x = (const float*)d_in[0];
  const float* w[3][4]; const float* bia[3][4];
  for (int p = 0; p < 3; p++) {
    w[p][0] = (const float*)d_in[1 + 8 * p + 0]; bia[p][0] = (const float*)d_in[1 + 8 * p + 1];
    w[p][1] = (const float*)d_in[1 + 8 * p + 2]; bia[p][1] = (const float*)d_in[1 + 8 * p + 3];
    w[p][2] = (const float*)d_in[1 + 8 * p + 4]; bia[p][2] = (const float*)d_in[1 + 8 * p + 5];
    w[p][3] = (const float*)d_in[1 + 8 * p + 6]; bia[p][3] = (const float*)d_in[1 + 8 * p + 7];
  }
  const float* cs_key = (const float*)d_in[25];
  const float* ng[4]; const float* nb[4];
  for (int i = 0; i < 4; i++) { ng[i] = (const float*)d_in[26 + 2 * i]; nb[i] = (const float*)d_in[27 + 2 * i]; }
  const float* m_w1[2]; const float* m_b1[2]; const float* m_w2[2]; const float* m_b2[2];
  for (int i = 0; i < 2; i++) {
    m_w1[i] = (const float*)d_in[34 + 4 * i]; m_b1[i] = (const float*)d_in[35 + 4 * i];
    m_w2[i] = (const float*)d_in[36 + 4 * i]; m_b2[i] = (const float*)d_in[37 + 4 * i];
  }

  // ---- workspace ----
  char* base = (char*)d_ws; size_t off = 0;
  auto alloc = [&](size_t bytes) -> void* {
    off = (off + 255) & ~(size_t)255;
    void* p = base + off; off += bytes; return p;
  };
  const size_t W1M = (size_t)1024 * 1024;
  unsigned short* W3ct = (unsigned short*)alloc(3 * W1M * 2);  // [wqT; wkT; wkvT]
  unsigned short* W3hp = (unsigned short*)alloc(3 * W1M * 2);
  unsigned short* Woct = (unsigned short*)alloc(W1M * 2);
  unsigned short* Wohp = (unsigned short*)alloc(W1M * 2);
  unsigned short* Wocs = (unsigned short*)alloc(W1M * 2);
  unsigned short* Wqcs = (unsigned short*)alloc(W1M * 2);
  unsigned short* Wkcs = (unsigned short*)alloc(W1M * 2);
  unsigned short* Wvcs = (unsigned short*)alloc(W1M * 2);
  unsigned short* Wm1u = (unsigned short*)alloc((size_t)4096 * 1024 * 2);
  unsigned short* Wm1d = (unsigned short*)alloc((size_t)1024 * 4096 * 2);
  unsigned short* Wm2u = (unsigned short*)alloc((size_t)4096 * 1024 * 2);
  unsigned short* Wm2d = (unsigned short*)alloc((size_t)1024 * 4096 * 2);
  unsigned short* BtQK = (unsigned short*)alloc((size_t)256 * 1024 * 2);
  float* bqk = (float*)alloc(256 * 4);
  float* b3ct = (float*)alloc(3072 * 4);
  float* b3hp = (float*)alloc(3072 * 4);
  unsigned short* KeyB = (unsigned short*)alloc((size_t)10 * 1024 * 2);
  unsigned short* Kcs = (unsigned short*)alloc((size_t)10 * 1024 * 2);
  unsigned short* Vcs = (unsigned short*)alloc((size_t)10 * 1024 * 2);
  unsigned short* S[6];
  for (int i = 0; i < 6; i++) S[i] = (unsigned short*)alloc((size_t)M * 1024 * 2);
  if (off > ws_size) {
    fprintf(stderr, "kernel_launch: ws too small: need %zu have %zu\n", off, ws_size);
    return;
  }
  // fold scratch aliased into S1 (dead during prep)
  unsigned short* Wvt_ct = S[1];
  unsigned short* Wraw_ct = S[1] + W1M;
  unsigned short* Wvt_hp = S[1] + 2 * W1M;
  unsigned short* Wraw_hp = S[1] + 3 * W1M;

  // big GEMMs: N%256 wide ones on k_gemm8 (r11-proven); N=1024 on k_gemmN (2 blocks/CU test)
  auto gemm8 = [&](const unsigned short* Ap, const unsigned short* Bt, const float* bi,
                   unsigned short* Cp, int Mm, int Nn, int Kk, bool gelu) {
    dim3 gg(Nn / 256, Mm / 256);
    if (gelu) k_gemm8<true><<<gg, 512, 0, stream>>>(Ap, Bt, bi, Cp, Mm, Nn, Kk);
    else      k_gemm8<false><<<gg, 512, 0, stream>>>(Ap, Bt, bi, Cp, Mm, Nn, Kk);
  };
  auto gemmN = [&](const unsigned short* Ap, const unsigned short* Bt, const float* bi,
                   unsigned short* Cp, int Mm, int Nn, int Kk, bool gelu) {
    dim3 gg(Nn / 256, Mm / 128);
    if (gelu) k_gemmN<true><<<gg, 512, 0, stream>>>(Ap, Bt, bi, Cp, Mm, Nn, Kk);
    else      k_gemmN<false><<<gg, 512, 0, stream>>>(Ap, Bt, bi, Cp, Mm, Nn, Kk);
  };
  auto tc = [&](const float* src, unsigned short* dst) {
    k_tcast<<<dim3(32, 32), 256, 0, stream>>>(src, dst, 1024, 1024);
  };

  // ---- weight prep ----
  tc(w[0][0], W3ct); tc(w[0][1], W3ct + W1M);
  tc(w[2][0], W3hp); tc(w[2][1], W3hp + W1M);
  tc(w[0][3], Woct); tc(w[2][3], Wohp); tc(w[1][3], Wocs);
  tc(w[1][0], Wqcs); tc(w[1][1], Wkcs); tc(w[1][2], Wvcs);
  k_tcast<<<dim3(128, 32), 256, 0, stream>>>(m_w1[0], Wm1u, 1024, 4096);
  k_tcast<<<dim3(32, 128), 256, 0, stream>>>(m_w2[0], Wm1d, 4096, 1024);
  k_tcast<<<dim3(128, 32), 256, 0, stream>>>(m_w1[1], Wm2u, 1024, 4096);
  k_tcast<<<dim3(32, 128), 256, 0, stream>>>(m_w2[1], Wm2d, 4096, 1024);
  tc(w[0][2], Wvt_ct); k_cast<<<1024, 256, 0, stream>>>(w[0][1], Wraw_ct, 262144);
  tc(w[2][2], Wvt_hp); k_cast<<<1024, 256, 0, stream>>>(w[2][1], Wraw_hp, 262144);
  k_cast<<<16384, 256, 0, stream>>>(x, S[0], 16777216 / 4);
  k_cast<<<10, 256, 0, stream>>>(cs_key, KeyB, 10240 / 4);
  // folded V weights (1024^3)
  k_gemmS<<<dim3(8, 8), 256, 0, stream>>>(Wvt_ct, Wraw_ct, nullptr, W3ct + 2 * W1M, 1024, 1024, 1024);
  k_gemmS<<<dim3(8, 8), 256, 0, stream>>>(Wvt_hp, Wraw_hp, nullptr, W3hp + 2 * W1M, 1024, 1024, 1024);
  // folded biases
  k_cpb<<<4, 256, 0, stream>>>(bia[0][0], bia[0][1], b3ct);
  k_bfold<<<4, 256, 0, stream>>>(bia[0][1], w[0][2], bia[0][2], b3ct + 2048);
  k_cpb<<<4, 256, 0, stream>>>(bia[2][0], bia[2][1], b3hp);
  k_bfold<<<4, 256, 0, stream>>>(bia[2][1], w[2][2], bia[2][2], b3hp + 2048);
  // cs stored patterns + scores fold
  k_gemm10<<<dim3(10, 16), 256, 0, stream>>>(KeyB, Wkcs, bia[1][1], Kcs);
  k_gemm10<<<dim3(10, 16), 256, 0, stream>>>(Kcs, Wvcs, bia[1][2], Vcs);
  k_wqk<<<256, 256, 0, stream>>>(Wqcs, bia[1][0], Kcs, BtQK, bqk);

  // ---- stage T (L=S=64 attention over seg) ----
  gemm8(S[0], W3ct, b3ct, S[1], M, 3072, 1024, false);                      // QKV -> S1..S3
  k_attn<64, 64, false><<<256 * 16, 256, 0, stream>>>(S[1], S[1] + 1024, S[1] + 2048, S[4], 3072);
  gemmN(S[4], Woct, bia[0][3], S[5], M, 1024, 1024, false);                 // enc -> S5
  k_ln<0, false><<<M, 256, 0, stream>>>(S[0], S[5], ng[0], nb[0], S[1]);    // D -> S1
  gemm8(S[1], Wm1u, m_b1[0], S[2], M, 4096, 1024, true);                    // H -> S2..S5
  gemmN(S[2], Wm1d, m_b2[0], S[0], M, 1024, 4096, false);                   // R -> S0
  k_ln<1, false><<<M, 256, 0, stream>>>(S[1], S[0], ng[1], nb[1], S[2]);    // S_in -> S2 (permuted)

  // ---- stage S (L=32) ----
  gemm8(S[2], W3hp, b3hp, S[3], M, 3072, 1024, false);                      // QKVhp -> S3..S5
  k_attn<32, 32, false><<<512 * 16, 256, 0, stream>>>(S[3], S[3] + 1024, S[3] + 2048, S[0], 3072);
  gemmN(S[0], Wohp, bia[2][3], S[1], M, 1024, 1024, false);                 // PH -> S1
  // cs-Hopfield: folded scores -> entmax10 -> PV in MIX layout -> out-proj
  k_gemmS<<<dim3(2, 128), 256, 0, stream>>>(S[2], BtQK, bqk, S[0], M, 256, 1024);   // SC -> S0[0:8M]
  k_entmax10<<<M / 16, 256, 0, stream>>>(S[0], S[0] + (size_t)M * 256);             // A -> S0[8M:16M]
  k_pvmix<<<M, 256, 0, stream>>>(S[0] + (size_t)M * 256, Vcs, S[3]);                // mix -> S3
  gemmN(S[3], Wocs, bia[1][3], S[4], M, 1024, 1024, false);                 // SH -> S4
  k_ln<0, false><<<M, 256, 0, stream>>>(S[4], S[1], ng[2], nb[2], S[0]);    // DE -> S0
  gemm8(S[0], Wm2u, m_b1[1], S[1], M, 4096, 1024, true);                    // H -> S1..S4
  gemmN(S[1], Wm2d, m_b2[1], S[5], M, 1024, 4096, false);                   // R2 -> S5
  k_ln<2, true><<<M, 256, 0, stream>>>(S[0], S[5], ng[3], nb[3], d_out);    // final LN+permute f32
}

// Round 15
// 1581.696 us; speedup vs baseline: 2.7368x; 1.0224x over previous
//
#include <hip/hip_runtime.h>
#include <cstdio>

typedef __bf16 bf16x8 __attribute__((ext_vector_type(8)));
typedef float f32x4 __attribute__((ext_vector_type(4)));
typedef int i32x4 __attribute__((ext_vector_type(4)));
typedef unsigned short u16x4 __attribute__((ext_vector_type(4)));

__device__ __forceinline__ float bf2f(unsigned short u) {
  union { unsigned int i; float f; } x; x.i = ((unsigned int)u) << 16; return x.f;
}
__device__ __forceinline__ unsigned short f2bf(float f) {
  union { float f; unsigned int i; } x; x.f = f;
  unsigned int r = x.i + 0x7fffu + ((x.i >> 16) & 1u);
  return (unsigned short)(r >> 16);
}

// async global->LDS, 16B per lane; LDS dest is wave-uniform base + lane*16
__device__ __forceinline__ void gl2lds16(const unsigned short* g, unsigned short* l) {
  __builtin_amdgcn_global_load_lds((const __attribute__((address_space(1))) unsigned int*)g,
                                   (__attribute__((address_space(3))) unsigned int*)l, 16, 0, 0);
}

// ---------------- elementwise f32 -> bf16 cast (vec4) ----------------
__global__ __launch_bounds__(256) void k_cast(const float* __restrict__ in,
                                              unsigned short* __restrict__ out, int n4) {
  int i = blockIdx.x * 256 + threadIdx.x;
  if (i >= n4) return;
  f32x4 v = ((const f32x4*)in)[i];
  u16x4 o;
  o[0] = f2bf(v[0]); o[1] = f2bf(v[1]); o[2] = f2bf(v[2]); o[3] = f2bf(v[3]);
  ((u16x4*)out)[i] = o;
}

// -------- transpose-cast: src f32 [K][N] -> dst bf16 [N][K] --------
__global__ __launch_bounds__(256) void k_tcast(const float* __restrict__ src,
                                               unsigned short* __restrict__ dst,
                                               int K, int N) {
  __shared__ float tile[32][33];
  int gx = blockIdx.x * 32;  // N dim
  int gy = blockIdx.y * 32;  // K dim
  int t = threadIdx.x;
  int c = t & 31, r0 = t >> 5;
#pragma unroll
  for (int i = 0; i < 4; i++) {
    int r = r0 + i * 8;
    tile[r][c] = src[(size_t)(gy + r) * N + gx + c];
  }
  __syncthreads();
#pragma unroll
  for (int i = 0; i < 4; i++) {
    int r = r0 + i * 8;
    dst[(size_t)(gx + r) * K + gy + c] = f2bf(tile[c][r]);
  }
}

// -------- batched 1024x1024 transpose-cast: z selects (src,dst) pair --------
struct TCBatch { const float* src[12]; unsigned short* dst[12]; };
__global__ __launch_bounds__(256) void k_tcast_b(TCBatch p) {
  __shared__ float tile[32][33];
  const float* src = p.src[blockIdx.z];
  unsigned short* dst = p.dst[blockIdx.z];
  int gx = blockIdx.x * 32, gy = blockIdx.y * 32;
  int t = threadIdx.x;
  int c = t & 31, r0 = t >> 5;
#pragma unroll
  for (int i = 0; i < 4; i++) {
    int r = r0 + i * 8;
    tile[r][c] = src[(size_t)(gy + r) * 1024 + gx + c];
  }
  __syncthreads();
#pragma unroll
  for (int i = 0; i < 4; i++) {
    int r = r0 + i * 8;
    dst[(size_t)(gx + r) * 1024 + gy + c] = f2bf(tile[c][r]);
  }
}

// ---- folded bias: out[n] = bv[n] + sum_j bk[j]*wv[j][n]  (f32, 1024 wide) ----
__global__ __launch_bounds__(256) void k_bfold(const float* __restrict__ bk,
                                               const float* __restrict__ wv,
                                               const float* __restrict__ bv,
                                               float* __restrict__ out) {
  int n = blockIdx.x * 256 + threadIdx.x;
  float acc = bv[n];
#pragma unroll 8
  for (int j = 0; j < 1024; j++) acc += bk[j] * wv[(size_t)j * 1024 + n];
  out[n] = acc;
}

// ---- concat two 1024-f32 vectors into out[0..2047] ----
__global__ __launch_bounds__(256) void k_cpb(const float* __restrict__ a,
                                             const float* __restrict__ b,
                                             float* __restrict__ out) {
  int t = blockIdx.x * 256 + threadIdx.x;
  out[t] = a[t];
  out[1024 + t] = b[t];
}

// ---- cs-fold: BtQK[n=(h*16+s)][k] = sum_e wqT[h*64+e][k]*K[s][h*64+e]; bqk[n]=bq.K ----
__global__ __launch_bounds__(256) void k_wqk(const unsigned short* __restrict__ wqT,
                                             const float* __restrict__ bq,
                                             const unsigned short* __restrict__ Kcs,
                                             unsigned short* __restrict__ BtQK,
                                             float* __restrict__ bqk) {
  int n = blockIdx.x, h = n >> 4, s = n & 15, t = threadIdx.x;
  if (s >= 10) {
    ((u16x4*)(BtQK + (size_t)n * 1024))[t] = u16x4{0, 0, 0, 0};
    if (t == 0) bqk[n] = 0.f;
    return;
  }
  float acc[4] = {0.f, 0.f, 0.f, 0.f};
  for (int e = 0; e < 64; e++) {
    float kv = bf2f(Kcs[s * 1024 + h * 64 + e]);
    u16x4 rv = ((const u16x4*)(wqT + (size_t)(h * 64 + e) * 1024))[t];
#pragma unroll
    for (int i = 0; i < 4; i++) acc[i] += bf2f(rv[i]) * kv;
  }
  u16x4 o;
#pragma unroll
  for (int i = 0; i < 4; i++) o[i] = f2bf(acc[i]);
  ((u16x4*)(BtQK + (size_t)n * 1024))[t] = o;
  if (t == 0) {
    float b = 0.f;
    for (int e = 0; e < 64; e++) b += bq[h * 64 + e] * bf2f(Kcs[s * 1024 + h * 64 + e]);
    bqk[n] = b;
  }
}

// ---- entmax-1.5 over 10 stored patterns, fully in registers (thread = (row,head)) ----
__global__ __launch_bounds__(256) void k_entmax10(const unsigned short* __restrict__ SC,
                                                  unsigned short* __restrict__ A) {
  int t = threadIdx.x;
  int m = blockIdx.x * 16 + (t >> 4), h = t & 15;
  const unsigned short* p = SC + (size_t)m * 256 + h * 16;
  float xs[10], mx = -1e30f;
#pragma unroll
  for (int s = 0; s < 10; s++) { xs[s] = bf2f(p[s]) * 0.0625f; mx = fmaxf(mx, xs[s]); }
  float lo = mx - 1.f, hi = mx - 0.31622776601683794f;  // d^-0.5, d=10
#pragma unroll 1
  for (int it = 0; it < 26; it++) {
    float mid = 0.5f * (lo + hi);
    float f = 0.f;
#pragma unroll
    for (int s = 0; s < 10; s++) { float dd = fmaxf(xs[s] - mid, 0.f); f += dd * dd; }
    bool gt = f > 1.f;
    lo = gt ? mid : lo;
    hi = gt ? hi : mid;
  }
  float tau = 0.5f * (lo + hi), ps = 0.f;
#pragma unroll
  for (int s = 0; s < 10; s++) { float dd = fmaxf(xs[s] - tau, 0.f); xs[s] = dd * dd; ps += xs[s]; }
  float r = 1.f / ps;
  unsigned short* q = A + (size_t)m * 256 + h * 16;
  u16x4 o0, o1, o2, o3;
#pragma unroll
  for (int i = 0; i < 4; i++) o0[i] = f2bf(xs[i] * r);
#pragma unroll
  for (int i = 0; i < 4; i++) o1[i] = f2bf(xs[4 + i] * r);
  o2[0] = f2bf(xs[8] * r); o2[1] = f2bf(xs[9] * r); o2[2] = 0; o2[3] = 0;
  o3[0] = o3[1] = o3[2] = o3[3] = 0;
  ((u16x4*)q)[0] = o0; ((u16x4*)q)[1] = o1; ((u16x4*)q)[2] = o2; ((u16x4*)q)[3] = o3;
}

// ---- PV + Hopfield "mix": out_mix[(b*32+ln)][c] = sum_s A[b,h,l,s] * V[s][h*64+d]
// with h = ln>>1, l = (ln&1)*16 + (c>>6), d = c&63.  One block per output row.
__global__ __launch_bounds__(256) void k_pvmix(const unsigned short* __restrict__ A,
                                               const unsigned short* __restrict__ Vcs,
                                               unsigned short* __restrict__ Out) {
  __shared__ float Vs[10][64];
  __shared__ float Asm[16][10];
  const int row = blockIdx.x;
  const int b = row >> 5, ln = row & 31;
  const int h = ln >> 1, lbase = (ln & 1) * 16;
  const int t = threadIdx.x;
  if (t < 160) {
    int j = t / 10, s = t - j * 10;
    Asm[j][s] = bf2f(A[((size_t)(b * 32 + lbase + j)) * 256 + h * 16 + s]);
  }
  for (int idx = t; idx < 640; idx += 256) {
    int s = idx >> 6, d = idx & 63;
    Vs[s][d] = bf2f(Vcs[s * 1024 + h * 64 + d]);
  }
  __syncthreads();
  const int j = t >> 4, d0 = (t & 15) * 4;
  float acc[4] = {0.f, 0.f, 0.f, 0.f};
#pragma unroll
  for (int s = 0; s < 10; s++) {
    float a = Asm[j][s];
#pragma unroll
    for (int i = 0; i < 4; i++) acc[i] += a * Vs[s][d0 + i];
  }
  u16x4 o;
#pragma unroll
  for (int i = 0; i < 4; i++) o[i] = f2bf(acc[i]);
  ((u16x4*)(Out + (size_t)row * 1024))[t] = o;
}

// ======== r11-proven 8-phase-family GEMM: 256x256, BK=64 (all big GEMMs) ========
template <bool GELU>
__global__ __launch_bounds__(512, 2) void k_gemm8(const unsigned short* __restrict__ A,
                                                  const unsigned short* __restrict__ Bt,
                                                  const float* __restrict__ bias,
                                                  unsigned short* __restrict__ C,
                                                  int M, int N, int K) {
  __shared__ unsigned short As[2][256 * 64];
  __shared__ unsigned short Bs[2][256 * 64];
  const int rowA0 = blockIdx.y * 256, colB0 = blockIdx.x * 256;
  const int t = threadIdx.x, w = t >> 6, lane = t & 63;
  const int wm = w >> 2, wn = w & 3;
  const int g = lane >> 4, ra = lane & 15;
  const int koff0 = (((0 * 4 + g) ^ (ra & 7)) * 8);
  const int koff1 = (((1 * 4 + g) ^ (ra & 7)) * 8);
  const int srow = w * 8 + (lane >> 3);
  const int schunk = ((lane & 7) ^ ((lane >> 3) & 7)) * 8;

  f32x4 acc[8][4] = {};

  auto stageA = [&](int buf, int kk) {
#pragma unroll
    for (int gq = 0; gq < 4; gq++)
      gl2lds16(A + (size_t)(rowA0 + gq * 64 + srow) * K + kk + schunk,
               &As[buf][gq * 4096 + w * 512]);
  };
  auto stageB = [&](int buf, int kk) {
#pragma unroll
    for (int gq = 0; gq < 4; gq++)
      gl2lds16(Bt + (size_t)(colB0 + gq * 64 + srow) * K + kk + schunk,
               &Bs[buf][gq * 4096 + w * 512]);
  };

  const int NT = K >> 6;
  stageA(0, 0); stageB(0, 0);
  if (NT > 1) { stageA(1, 64); stageB(1, 64); }
  if (NT > 1) asm volatile("s_waitcnt vmcnt(8)" ::: "memory");
  else        asm volatile("s_waitcnt vmcnt(0)" ::: "memory");
  __builtin_amdgcn_sched_barrier(0);
  __builtin_amdgcn_s_barrier();

  bf16x8 aH[4][2], bH[2][2][2];
  const int arow0 = wm * 128, brow0 = wn * 64;
  for (int j = 0; j < NT; ++j) {
    const int buf = j & 1;
    const unsigned short* Ab = &As[buf][0];
    const unsigned short* Bb = &Bs[buf][0];
    // phase 0
#pragma unroll
    for (int fr = 0; fr < 4; fr++) {
      aH[fr][0] = *(const bf16x8*)&Ab[(arow0 + fr * 16 + ra) * 64 + koff0];
      aH[fr][1] = *(const bf16x8*)&Ab[(arow0 + fr * 16 + ra) * 64 + koff1];
    }
#pragma unroll
    for (int fc = 0; fc < 2; fc++) {
      bH[0][fc][0] = *(const bf16x8*)&Bb[(brow0 + fc * 16 + ra) * 64 + koff0];
      bH[0][fc][1] = *(const bf16x8*)&Bb[(brow0 + fc * 16 + ra) * 64 + koff1];
    }
    __builtin_amdgcn_sched_barrier(0);
    __builtin_amdgcn_s_barrier();
    __builtin_amdgcn_sched_barrier(0);
    __builtin_amdgcn_s_setprio(1);
#pragma unroll
    for (int fr = 0; fr < 4; fr++)
#pragma unroll
      for (int fc = 0; fc < 2; fc++)
#pragma unroll
        for (int ks = 0; ks < 2; ks++)
          acc[fr][fc] = __builtin_amdgcn_mfma_f32_16x16x32_bf16(aH[fr][ks], bH[0][fc][ks], acc[fr][fc], 0, 0, 0);
    __builtin_amdgcn_s_setprio(0);
    __builtin_amdgcn_sched_barrier(0);
    __builtin_amdgcn_s_barrier();
    // phase 1
#pragma unroll
    for (int fc = 0; fc < 2; fc++) {
      bH[1][fc][0] = *(const bf16x8*)&Bb[(brow0 + 32 + fc * 16 + ra) * 64 + koff0];
      bH[1][fc][1] = *(const bf16x8*)&Bb[(brow0 + 32 + fc * 16 + ra) * 64 + koff1];
    }
    __builtin_amdgcn_sched_barrier(0);
    __builtin_amdgcn_s_barrier();
    __builtin_amdgcn_sched_barrier(0);
    __builtin_amdgcn_s_setprio(1);
#pragma unroll
    for (int fr = 0; fr < 4; fr++)
#pragma unroll
      for (int fc = 0; fc < 2; fc++)
#pragma unroll
        for (int ks = 0; ks < 2; ks++)
          acc[fr][2 + fc] = __builtin_amdgcn_mfma_f32_16x16x32_bf16(aH[fr][ks], bH[1][fc][ks], acc[fr][2 + fc], 0, 0, 0);
    __builtin_amdgcn_s_setprio(0);
    __builtin_amdgcn_sched_barrier(0);
    __builtin_amdgcn_s_barrier();
    // phase 2: stage B(j+2) into same buf (B(j) reads done)
#pragma unroll
    for (int fr = 0; fr < 4; fr++) {
      aH[fr][0] = *(const bf16x8*)&Ab[(arow0 + 64 + fr * 16 + ra) * 64 + koff0];
      aH[fr][1] = *(const bf16x8*)&Ab[(arow0 + 64 + fr * 16 + ra) * 64 + koff1];
    }
    if (j + 2 < NT) stageB(buf, (j + 2) << 6);
    __builtin_amdgcn_sched_barrier(0);
    __builtin_amdgcn_s_barrier();
    __builtin_amdgcn_sched_barrier(0);
    __builtin_amdgcn_s_setprio(1);
#pragma unroll
    for (int fr = 0; fr < 4; fr++)
#pragma unroll
      for (int fc = 0; fc < 2; fc++)
#pragma unroll
        for (int ks = 0; ks < 2; ks++)
          acc[4 + fr][fc] = __builtin_amdgcn_mfma_f32_16x16x32_bf16(aH[fr][ks], bH[0][fc][ks], acc[4 + fr][fc], 0, 0, 0);
    __builtin_amdgcn_s_setprio(0);
    __builtin_amdgcn_sched_barrier(0);
    __builtin_amdgcn_s_barrier();
    // phase 3: stage A(j+2); counted boundary
    if (j + 2 < NT) stageA(buf, (j + 2) << 6);
    __builtin_amdgcn_sched_barrier(0);
    __builtin_amdgcn_s_setprio(1);
#pragma unroll
    for (int fr = 0; fr < 4; fr++)
#pragma unroll
      for (int fc = 0; fc < 2; fc++)
#pragma unroll
        for (int ks = 0; ks < 2; ks++)
          acc[4 + fr][2 + fc] = __builtin_amdgcn_mfma_f32_16x16x32_bf16(aH[fr][ks], bH[1][fc][ks], acc[4 + fr][2 + fc], 0, 0, 0);
    __builtin_amdgcn_s_setprio(0);
    if (j + 1 < NT) {
      if (j + 2 < NT) asm volatile("s_waitcnt vmcnt(8)" ::: "memory");
      else            asm volatile("s_waitcnt vmcnt(0)" ::: "memory");
    }
    __builtin_amdgcn_sched_barrier(0);
    __builtin_amdgcn_s_barrier();
  }
  asm volatile("s_waitcnt vmcnt(0) lgkmcnt(0)" ::: "memory");
  __builtin_amdgcn_s_barrier();

  unsigned short* Ep = &As[0][0] + w * 1024;
  const int grow0 = rowA0 + wm * 128;
  const int gcol0 = colB0 + wn * 64;
  float bv[4];
#pragma unroll
  for (int n = 0; n < 4; n++) bv[n] = bias ? bias[gcol0 + n * 16 + ra] : 0.f;
  const int rdrow = lane >> 3, rg = lane & 7;
#pragma unroll
  for (int m = 0; m < 8; m++) {
#pragma unroll
    for (int n = 0; n < 4; n++)
#pragma unroll
      for (int i = 0; i < 4; i++) {
        int r = g * 4 + i;
        float v = acc[m][n][i] + bv[n];
        if (GELU) v = 0.5f * v * (1.f + erff(v * 0.70710678118654752f));
        Ep[r * 64 + ((ra + n * 16) ^ ((r & 7) << 3))] = f2bf(v);
      }
    asm volatile("s_waitcnt lgkmcnt(0)" ::: "memory");
    __builtin_amdgcn_sched_barrier(0);
#pragma unroll
    for (int p = 0; p < 2; p++) {
      int rr = p * 8 + rdrow;
      bf16x8 val = *(const bf16x8*)&Ep[rr * 64 + ((rg ^ (rr & 7)) << 3)];
      *(bf16x8*)&C[(size_t)(grow0 + m * 16 + rr) * N + gcol0 + rg * 8] = val;
    }
    asm volatile("s_waitcnt lgkmcnt(0)" ::: "memory");
  }
}

// ======== small MFMA GEMM (folds + skinny cs GEMMs): 128^2 tile, ring-3 ========
__global__ __launch_bounds__(256) void k_gemmS(const unsigned short* __restrict__ A,
                                               const unsigned short* __restrict__ Bt,
                                               const float* __restrict__ bias,
                                               unsigned short* __restrict__ C,
                                               int M, int N, int K) {
  __shared__ unsigned short As[3][128 * 32];
  __shared__ unsigned short Bs[3][128 * 32];
  const int rowA0 = blockIdx.y * 128, colB0 = blockIdx.x * 128;
  const int t = threadIdx.x, w = t >> 6, lane = t & 63;
  const int wr = w >> 1, wc = w & 1;
  const int srow = w * 16 + (lane >> 2);
  const int schunk = (lane & 3) ^ ((lane >> 3) & 3);
  const unsigned short* pa = A + (size_t)(rowA0 + srow) * K + schunk * 8;
  const unsigned short* pb = Bt + (size_t)(colB0 + srow) * K + schunk * 8;
  const size_t row64 = (size_t)64 * K;
  f32x4 acc[4][4] = {};
  const int g = lane >> 4, ra = lane & 15;
  const int gp8 = (g ^ ((ra >> 1) & 3)) * 8;
  auto stage = [&](int buf, int kk) {
    gl2lds16(pa + kk, &As[buf][w * 512]);
    gl2lds16(pa + row64 + kk, &As[buf][2048 + w * 512]);
    gl2lds16(pb + kk, &Bs[buf][w * 512]);
    gl2lds16(pb + row64 + kk, &Bs[buf][2048 + w * 512]);
  };
  const int NT = K >> 5;
  stage(0, 0);
  if (NT > 1) stage(1, 32);
  int cur = 0;
  for (int j = 0; j < NT; ++j) {
    if (j + 1 < NT) asm volatile("s_waitcnt vmcnt(4)" ::: "memory");
    else            asm volatile("s_waitcnt vmcnt(0)" ::: "memory");
    __syncthreads();
    if (j + 2 < NT) { int nb = cur + 2; if (nb >= 3) nb -= 3; stage(nb, (j + 2) * 32); }
    bf16x8 af[4], bfr[4];
#pragma unroll
    for (int m = 0; m < 4; m++)
      af[m] = *(const bf16x8*)&As[cur][(wr * 64 + m * 16 + ra) * 32 + gp8];
#pragma unroll
    for (int n = 0; n < 4; n++)
      bfr[n] = *(const bf16x8*)&Bs[cur][(wc * 64 + n * 16 + ra) * 32 + gp8];
#pragma unroll
    for (int m = 0; m < 4; m++)
#pragma unroll
      for (int n = 0; n < 4; n++)
        acc[m][n] = __builtin_amdgcn_mfma_f32_16x16x32_bf16(af[m], bfr[n], acc[m][n], 0, 0, 0);
    __syncthreads();
    cur += 1; if (cur >= 3) cur -= 3;
  }
  const int cr = g * 4, cc = ra;
#pragma unroll
  for (int m = 0; m < 4; m++) {
    int grow = rowA0 + wr * 64 + m * 16 + cr;
#pragma unroll
    for (int n = 0; n < 4; n++) {
      int gcol = colB0 + wc * 64 + n * 16 + cc;
      float bvv = bias ? bias[gcol] : 0.f;
#pragma unroll
      for (int i = 0; i < 4; i++)
        C[(size_t)(grow + i) * N + gcol] = f2bf(acc[m][n][i] + bvv);
    }
  }
}

// ---------------- small GEMM (M<=10): C[Mr][1024] = A[Mr][1024] * Wt^T + bias ----------------
__global__ __launch_bounds__(256) void k_gemm10(const unsigned short* __restrict__ A,
                                                const unsigned short* __restrict__ Bt,
                                                const float* __restrict__ bias,
                                                unsigned short* __restrict__ C) {
  __shared__ float af[1024];
  int m = blockIdx.x, nb = blockIdx.y;
  int t = threadIdx.x;
#pragma unroll
  for (int i = 0; i < 4; i++) af[t * 4 + i] = bf2f(A[(size_t)m * 1024 + t * 4 + i]);
  __syncthreads();
  int w = t >> 6, lane = t & 63;
  for (int n = nb * 64 + w; n < nb * 64 + 64; n += 4) {
    const unsigned short* brow = Bt + (size_t)n * 1024 + lane * 16;
    float acc = 0.f;
#pragma unroll
    for (int j = 0; j < 16; j++) acc += af[lane * 16 + j] * bf2f(brow[j]);
#pragma unroll
    for (int o = 32; o; o >>= 1) acc += __shfl_xor(acc, o);
    if (lane == 0) C[(size_t)m * 1024 + n] = f2bf(acc + bias[n]);
  }
}

// ---------------- entmax-1.5 attention, MFMA version (RS = input row stride) ----------------
template <int L, int S, bool SHARED>
__global__ __launch_bounds__(256) void k_attn(const unsigned short* __restrict__ Q,
                                              const unsigned short* __restrict__ Kb,
                                              const unsigned short* __restrict__ Vb,
                                              unsigned short* __restrict__ Out, int RS) {
  constexpr int SP = (S <= 32) ? 32 : 64;
  constexpr int QST = 72;
  constexpr int VST = SP + 8;
  constexpr int CST = SP + 4;
  __shared__ unsigned short Qs[L * QST];
  __shared__ unsigned short Ks[SP * QST];
  __shared__ unsigned short Vt[64 * VST];
  __shared__ float Sc[L * CST];
  __shared__ float Rps[L];
  const int blk = blockIdx.x, batch = blk >> 4, h = blk & 15;
  const int t = threadIdx.x, w = t >> 6, lane = t & 63;
  for (int c = t; c < L * 8; c += 256) {
    int r = c >> 3, ch = (c & 7) * 8;
    *(i32x4*)&Qs[r * QST + ch] =
        *(const i32x4*)&Q[((size_t)(batch * L + r)) * RS + h * 64 + ch];
  }
  for (int c = t; c < SP * 8; c += 256) {
    int r = c >> 3, ch = (c & 7) * 8;
    i32x4 v = {0, 0, 0, 0};
    if (r < S) {
      size_t rb = SHARED ? (size_t)r : (size_t)(batch * S + r);
      v = *(const i32x4*)&Kb[rb * RS + h * 64 + ch];
    }
    *(i32x4*)&Ks[r * QST + ch] = v;
  }
  for (int c = t; c < SP * 64; c += 256) {
    int s = c >> 6, e = c & 63;
    unsigned short v = 0;
    if (s < S) {
      size_t rb = SHARED ? (size_t)s : (size_t)(batch * S + s);
      v = Vb[rb * RS + h * 64 + e];
    }
    Vt[e * VST + s] = v;
  }
  __syncthreads();
  const int ka = (lane >> 4) * 8, ra = lane & 15;
  const int cr = (lane >> 4) * 4, cc = lane & 15;
  constexpr int NT = SP / 16, TT = (L / 16) * NT;
  for (int tt = w; tt < TT; tt += 4) {
    int m = tt / NT, n = tt % NT;
    f32x4 a = {0.f, 0.f, 0.f, 0.f};
#pragma unroll
    for (int ks = 0; ks < 2; ks++) {
      bf16x8 af = *(const bf16x8*)&Qs[(m * 16 + ra) * QST + ks * 32 + ka];
      bf16x8 bf = *(const bf16x8*)&Ks[(n * 16 + ra) * QST + ks * 32 + ka];
      a = __builtin_amdgcn_mfma_f32_16x16x32_bf16(af, bf, a, 0, 0, 0);
    }
#pragma unroll
    for (int i = 0; i < 4; i++)
      Sc[(m * 16 + cr + i) * CST + n * 16 + cc] = a[i] * 0.0625f;
  }
  __syncthreads();
  constexpr int G = 256 / L, RW = 64 / G, SL = SP / G;
  const int row = w * RW + lane / G, sub = lane % G;
  float xs[SL];
#pragma unroll
  for (int j = 0; j < SL; j++) {
    int s = sub * SL + j;
    float v = Sc[row * CST + s];
    if (S < SP && s >= S) v = -1e30f;
    xs[j] = v;
  }
  float mx = xs[0];
#pragma unroll
  for (int j = 1; j < SL; j++) mx = fmaxf(mx, xs[j]);
#pragma unroll
  for (int o = G / 2; o; o >>= 1) mx = fmaxf(mx, __shfl_xor(mx, o));
  const float hoff = (S == 64) ? 0.125f : (S == 32) ? 0.17677669529663687f : 0.31622776601683794f;
  float lo = mx - 1.f, hi = mx - hoff;
#pragma unroll 1
  for (int it = 0; it < 26; it++) {
    float mid = 0.5f * (lo + hi);
    float f = 0.f;
#pragma unroll
    for (int j = 0; j < SL; j++) { float dd = fmaxf(xs[j] - mid, 0.f); f += dd * dd; }
#pragma unroll
    for (int o = G / 2; o; o >>= 1) f += __shfl_xor(f, o);
    bool gt = f > 1.f;
    lo = gt ? mid : lo;
    hi = gt ? hi : mid;
  }
  float tau = 0.5f * (lo + hi);
  float ps = 0.f;
#pragma unroll
  for (int j = 0; j < SL; j++) { float dd = fmaxf(xs[j] - tau, 0.f); xs[j] = dd * dd; ps += xs[j]; }
#pragma unroll
  for (int o = G / 2; o; o >>= 1) ps += __shfl_xor(ps, o);
  if (sub == 0) Rps[row] = 1.f / ps;
  unsigned short* Pb = Qs;
#pragma unroll
  for (int j = 0; j < SL; j += 4) {
    u16x4 pv;
#pragma unroll
    for (int jj = 0; jj < 4; jj++) pv[jj] = f2bf(xs[j + jj]);
    *(u16x4*)&Pb[row * VST + sub * SL + j] = pv;
  }
  __syncthreads();
  constexpr int TT2 = (L / 16) * 4;
  for (int tt = w; tt < TT2; tt += 4) {
    int m = tt >> 2, n = tt & 3;
    f32x4 a = {0.f, 0.f, 0.f, 0.f};
#pragma unroll
    for (int ks = 0; ks < SP / 32; ks++) {
      bf16x8 af = *(const bf16x8*)&Pb[(m * 16 + ra) * VST + ks * 32 + ka];
      bf16x8 bf = *(const bf16x8*)&Vt[(n * 16 + ra) * VST + ks * 32 + ka];
      a = __builtin_amdgcn_mfma_f32_16x16x32_bf16(af, bf, a, 0, 0, 0);
    }
#pragma unroll
    for (int i = 0; i < 4; i++) {
      int l = m * 16 + cr + i, e = n * 16 + cc;
      float val = a[i] * Rps[l];
      int l_new = h * (L / 16) + (l >> 4);
      int cg = (l & 15) * 64 + e;
      Out[((size_t)(batch * L + l_new)) * 1024 + cg] = f2bf(val);
    }
  }
}

// ---------------- LayerNorm(a+b) * g + be, optional row permutation / f32 out ----------------
template <int MODE, bool F32OUT>
__global__ __launch_bounds__(256) void k_ln(const unsigned short* __restrict__ a,
                                            const unsigned short* __restrict__ b,
                                            const float* __restrict__ g,
                                            const float* __restrict__ be,
                                            void* __restrict__ outp) {
  __shared__ float red[8];
  int r = blockIdx.x, t = threadIdx.x;
  size_t base = (size_t)r * 1024 + t * 4;
  u16x4 av = *(const u16x4*)(a + base);
  u16x4 bv = *(const u16x4*)(b + base);
  float x[4];
  float s = 0.f, ss = 0.f;
#pragma unroll
  for (int i = 0; i < 4; i++) {
    x[i] = bf2f(av[i]) + bf2f(bv[i]);
    s += x[i]; ss += x[i] * x[i];
  }
#pragma unroll
  for (int o = 32; o; o >>= 1) { s += __shfl_xor(s, o); ss += __shfl_xor(ss, o); }
  int w = t >> 6;
  if ((t & 63) == 0) { red[w] = s; red[4 + w] = ss; }
  __syncthreads();
  s = red[0] + red[1] + red[2] + red[3];
  ss = red[4] + red[5] + red[6] + red[7];
  float mean = s * (1.f / 1024.f);
  float var = ss * (1.f / 1024.f) - mean * mean;
  float rstd = rsqrtf(var + 1e-5f);
  int orow;
  if (MODE == 0) orow = r;
  else if (MODE == 1) { int bi = r >> 11, rem = r & 2047; int tt = rem >> 6, sd = rem & 63; orow = (bi << 11) + sd * 32 + tt; }
  else { int bi = r >> 11, rem = r & 2047; int sd = rem >> 5, tt = rem & 31; orow = (bi << 11) + tt * 64 + sd; }
  size_t ob = (size_t)orow * 1024 + t * 4;
  if (F32OUT) {
    f32x4 y;
#pragma unroll
    for (int i = 0; i < 4; i++) y[i] = (x[i] - mean) * rstd * g[t * 4 + i] + be[t * 4 + i];
    *(f32x4*)((float*)outp + ob) = y;
  } else {
    u16x4 y;
#pragma unroll
    for (int i = 0; i < 4; i++) y[i] = f2bf((x[i] - mean) * rstd * g[t * 4 + i] + be[t * 4 + i]);
    *(u16x4*)((unsigned short*)outp + ob) = y;
  }
}

// =======================================================================================

extern "C" void kernel_launch(void* const* d_in, const int* in_sizes, int n_in,
                              void* d_out, int out_size, void* d_ws, size_t ws_size,
                              hipStream_t stream) {
  const int M = 16384;
  if (n_in < 43 || in_sizes[0] != 16777216 || in_sizes[25] != 10240 || in_sizes[34] != 4194304) {
    fprintf(stderr, "kernel_launch: unexpected input layout (n_in=%d)\n", n_in);
    return;
  }
  const float* x = (const float*)d_in[0];
  const float* w[3][4]; const float* bia[3][4];
  for (int p = 0; p < 3; p++) {
    w[p][0] = (const float*)d_in[1 + 8 * p + 0]; bia[p][0] = (const float*)d_in[1 + 8 * p + 1];
    w[p][1] = (const float*)d_in[1 + 8 * p + 2]; bia[p][1] = (const float*)d_in[1 + 8 * p + 3];
    w[p][2] = (const float*)d_in[1 + 8 * p + 4]; bia[p][2] = (const float*)d_in[1 + 8 * p + 5];
    w[p][3] = (const float*)d_in[1 + 8 * p + 6]; bia[p][3] = (const float*)d_in[1 + 8 * p + 7];
  }
  const float* cs_key = (const float*)d_in[25];
  const float* ng[4]; const float* nb[4];
  for (int i = 0; i < 4; i++) { ng[i] = (const float*)d_in[26 + 2 * i]; nb[i] = (const float*)d_in[27 + 2 * i]; }
  const float* m_w1[2]; const float* m_b1[2]; const float* m_w2[2]; const float* m_b2[2];
  for (int i = 0; i < 2; i++) {
    m_w1[i] = (const float*)d_in[34 + 4 * i]; m_b1[i] = (const float*)d_in[35 + 4 * i];
    m_w2[i] = (const float*)d_in[36 + 4 * i]; m_b2[i] = (const float*)d_in[37 + 4 * i];
  }

  // ---- workspace ----
  char* base = (char*)d_ws; size_t off = 0;
  auto alloc = [&](size_t bytes) -> void* {
    off = (off + 255) & ~(size_t)255;
    void* p = base + off; off += bytes; return p;
  };
  const size_t W1M = (size_t)1024 * 1024;
  unsigned short* W3ct = (unsigned short*)alloc(3 * W1M * 2);  // [wqT; wkT; wkvT]
  unsigned short* W3hp = (unsigned short*)alloc(3 * W1M * 2);
  unsigned short* Woct = (unsigned short*)alloc(W1M * 2);
  unsigned short* Wohp = (unsigned short*)alloc(W1M * 2);
  unsigned short* Wocs = (unsigned short*)alloc(W1M * 2);
  unsigned short* Wqcs = (unsigned short*)alloc(W1M * 2);
  unsigned short* Wkcs = (unsigned short*)alloc(W1M * 2);
  unsigned short* Wvcs = (unsigned short*)alloc(W1M * 2);
  unsigned short* Wm1u = (unsigned short*)alloc((size_t)4096 * 1024 * 2);
  unsigned short* Wm1d = (unsigned short*)alloc((size_t)1024 * 4096 * 2);
  unsigned short* Wm2u = (unsigned short*)alloc((size_t)4096 * 1024 * 2);
  unsigned short* Wm2d = (unsigned short*)alloc((size_t)1024 * 4096 * 2);
  unsigned short* BtQK = (unsigned short*)alloc((size_t)256 * 1024 * 2);
  float* bqk = (float*)alloc(256 * 4);
  float* b3ct = (float*)alloc(3072 * 4);
  float* b3hp = (float*)alloc(3072 * 4);
  unsigned short* KeyB = (unsigned short*)alloc((size_t)10 * 1024 * 2);
  unsigned short* Kcs = (unsigned short*)alloc((size_t)10 * 1024 * 2);
  unsigned short* Vcs = (unsigned short*)alloc((size_t)10 * 1024 * 2);
  unsigned short* S[6];
  for (int i = 0; i < 6; i++) S[i] = (unsigned short*)alloc((size_t)M * 1024 * 2);
  if (off > ws_size) {
    fprintf(stderr, "kernel_launch: ws too small: need %zu have %zu\n", off, ws_size);
    return;
  }
  // fold scratch aliased into S1 (dead during prep)
  unsigned short* Wvt_ct = S[1];
  unsigned short* Wraw_ct = S[1] + W1M;
  unsigned short* Wvt_hp = S[1] + 2 * W1M;
  unsigned short* Wraw_hp = S[1] + 3 * W1M;

  auto gemm8 = [&](const unsigned short* Ap, const unsigned short* Bt, const float* bi,
                   unsigned short* Cp, int Mm, int Nn, int Kk, bool gelu) {
    dim3 gg(Nn / 256, Mm / 256);
    if (gelu) k_gemm8<true><<<gg, 512, 0, stream>>>(Ap, Bt, bi, Cp, Mm, Nn, Kk);
    else      k_gemm8<false><<<gg, 512, 0, stream>>>(Ap, Bt, bi, Cp, Mm, Nn, Kk);
  };

  // ---- weight prep (batched 1024^2 transposes: 12 -> 1 launch) ----
  TCBatch tcb;
  tcb.src[0] = w[0][0];  tcb.dst[0] = W3ct;
  tcb.src[1] = w[0][1];  tcb.dst[1] = W3ct + W1M;
  tcb.src[2] = w[2][0];  tcb.dst[2] = W3hp;
  tcb.src[3] = w[2][1];  tcb.dst[3] = W3hp + W1M;
  tcb.src[4] = w[0][3];  tcb.dst[4] = Woct;
  tcb.src[5] = w[2][3];  tcb.dst[5] = Wohp;
  tcb.src[6] = w[1][3];  tcb.dst[6] = Wocs;
  tcb.src[7] = w[1][0];  tcb.dst[7] = Wqcs;
  tcb.src[8] = w[1][1];  tcb.dst[8] = Wkcs;
  tcb.src[9] = w[1][2];  tcb.dst[9] = Wvcs;
  tcb.src[10] = w[0][2]; tcb.dst[10] = Wvt_ct;
  tcb.src[11] = w[2][2]; tcb.dst[11] = Wvt_hp;
  k_tcast_b<<<dim3(32, 32, 12), 256, 0, stream>>>(tcb);
  k_tcast<<<dim3(128, 32), 256, 0, stream>>>(m_w1[0], Wm1u, 1024, 4096);
  k_tcast<<<dim3(32, 128), 256, 0, stream>>>(m_w2[0], Wm1d, 4096, 1024);
  k_tcast<<<dim3(128, 32), 256, 0, stream>>>(m_w1[1], Wm2u, 1024, 4096);
  k_tcast<<<dim3(32, 128), 256, 0, stream>>>(m_w2[1], Wm2d, 4096, 1024);
  k_cast<<<1024, 256, 0, stream>>>(w[0][1], Wraw_ct, 262144);
  k_cast<<<1024, 256, 0, stream>>>(w[2][1], Wraw_hp, 262144);
  k_cast<<<16384, 256, 0, stream>>>(x, S[0], 16777216 / 4);
  k_cast<<<10, 256, 0, stream>>>(cs_key, KeyB, 10240 / 4);
  // folded V weights (1024^3)
  k_gemmS<<<dim3(8, 8), 256, 0, stream>>>(Wvt_ct, Wraw_ct, nullptr, W3ct + 2 * W1M, 1024, 1024, 1024);
  k_gemmS<<<dim3(8, 8), 256, 0, stream>>>(Wvt_hp, Wraw_hp, nullptr, W3hp + 2 * W1M, 1024, 1024, 1024);
  // folded biases
  k_cpb<<<4, 256, 0, stream>>>(bia[0][0], bia[0][1], b3ct);
  k_bfold<<<4, 256, 0, stream>>>(bia[0][1], w[0][2], bia[0][2], b3ct + 2048);
  k_cpb<<<4, 256, 0, stream>>>(bia[2][0], bia[2][1], b3hp);
  k_bfold<<<4, 256, 0, stream>>>(bia[2][1], w[2][2], bia[2][2], b3hp + 2048);
  // cs stored patterns + scores fold
  k_gemm10<<<dim3(10, 16), 256, 0, stream>>>(KeyB, Wkcs, bia[1][1], Kcs);
  k_gemm10<<<dim3(10, 16), 256, 0, stream>>>(Kcs, Wvcs, bia[1][2], Vcs);
  k_wqk<<<256, 256, 0, stream>>>(Wqcs, bia[1][0], Kcs, BtQK, bqk);

  // ---- stage T (L=S=64 attention over seg) ----
  gemm8(S[0], W3ct, b3ct, S[1], M, 3072, 1024, false);                      // QKV -> S1..S3
  k_attn<64, 64, false><<<256 * 16, 256, 0, stream>>>(S[1], S[1] + 1024, S[1] + 2048, S[4], 3072);
  gemm8(S[4], Woct, bia[0][3], S[5], M, 1024, 1024, false);                 // enc -> S5
  k_ln<0, false><<<M, 256, 0, stream>>>(S[0], S[5], ng[0], nb[0], S[1]);    // D -> S1
  gemm8(S[1], Wm1u, m_b1[0], S[2], M, 4096, 1024, true);                    // H -> S2..S5
  gemm8(S[2], Wm1d, m_b2[0], S[0], M, 1024, 4096, false);                   // R -> S0
  k_ln<1, false><<<M, 256, 0, stream>>>(S[1], S[0], ng[1], nb[1], S[2]);    // S_in -> S2 (permuted)

  // ---- stage S (L=32) ----
  gemm8(S[2], W3hp, b3hp, S[3], M, 3072, 1024, false);                      // QKVhp -> S3..S5
  k_attn<32, 32, false><<<512 * 16, 256, 0, stream>>>(S[3], S[3] + 1024, S[3] + 2048, S[0], 3072);
  gemm8(S[0], Wohp, bia[2][3], S[1], M, 1024, 1024, false);                 // PH -> S1
  // cs-Hopfield: folded scores -> entmax10 -> PV in MIX layout -> out-proj
  k_gemmS<<<dim3(2, 128), 256, 0, stream>>>(S[2], BtQK, bqk, S[0], M, 256, 1024);   // SC -> S0[0:8M]
  k_entmax10<<<M / 16, 256, 0, stream>>>(S[0], S[0] + (size_t)M * 256);             // A -> S0[8M:16M]
  k_pvmix<<<M, 256, 0, stream>>>(S[0] + (size_t)M * 256, Vcs, S[3]);                // mix -> S3
  gemm8(S[3], Wocs, bia[1][3], S[4], M, 1024, 1024, false);                 // SH -> S4
  k_ln<0, false><<<M, 256, 0, stream>>>(S[4], S[1], ng[2], nb[2], S[0]);    // DE -> S0
  gemm8(S[0], Wm2u, m_b1[1], S[1], M, 4096, 1024, true);                    // H -> S1..S4
  gemm8(S[1], Wm2d, m_b2[1], S[5], M, 1024, 4096, false);                   // R2 -> S5
  k_ln<2, true><<<M, 256, 0, stream>>>(S[0], S[5], ng[3], nb[3], d_out);    // final LN+permute f32
}

// Round 16
// 1521.221 us; speedup vs baseline: 2.8456x; 1.0398x over previous
//
#include <hip/hip_runtime.h>
#include <cstdio>

typedef __bf16 bf16x8 __attribute__((ext_vector_type(8)));
typedef float f32x4 __attribute__((ext_vector_type(4)));
typedef int i32x4 __attribute__((ext_vector_type(4)));
typedef unsigned short u16x4 __attribute__((ext_vector_type(4)));

__device__ __forceinline__ float bf2f(unsigned short u) {
  union { unsigned int i; float f; } x; x.i = ((unsigned int)u) << 16; return x.f;
}
__device__ __forceinline__ unsigned short f2bf(float f) {
  union { float f; unsigned int i; } x; x.f = f;
  unsigned int r = x.i + 0x7fffu + ((x.i >> 16) & 1u);
  return (unsigned short)(r >> 16);
}

// async global->LDS, 16B per lane; LDS dest is wave-uniform base + lane*16
__device__ __forceinline__ void gl2lds16(const unsigned short* g, unsigned short* l) {
  __builtin_amdgcn_global_load_lds((const __attribute__((address_space(1))) unsigned int*)g,
                                   (__attribute__((address_space(3))) unsigned int*)l, 16, 0, 0);
}

// ---------------- elementwise f32 -> bf16 cast (vec4) ----------------
__global__ __launch_bounds__(256) void k_cast(const float* __restrict__ in,
                                              unsigned short* __restrict__ out, int n4) {
  int i = blockIdx.x * 256 + threadIdx.x;
  if (i >= n4) return;
  f32x4 v = ((const f32x4*)in)[i];
  u16x4 o;
  o[0] = f2bf(v[0]); o[1] = f2bf(v[1]); o[2] = f2bf(v[2]); o[3] = f2bf(v[3]);
  ((u16x4*)out)[i] = o;
}

// -------- transpose-cast: src f32 [K][N] -> dst bf16 [N][K] --------
__global__ __launch_bounds__(256) void k_tcast(const float* __restrict__ src,
                                               unsigned short* __restrict__ dst,
                                               int K, int N) {
  __shared__ float tile[32][33];
  int gx = blockIdx.x * 32;  // N dim
  int gy = blockIdx.y * 32;  // K dim
  int t = threadIdx.x;
  int c = t & 31, r0 = t >> 5;
#pragma unroll
  for (int i = 0; i < 4; i++) {
    int r = r0 + i * 8;
    tile[r][c] = src[(size_t)(gy + r) * N + gx + c];
  }
  __syncthreads();
#pragma unroll
  for (int i = 0; i < 4; i++) {
    int r = r0 + i * 8;
    dst[(size_t)(gx + r) * K + gy + c] = f2bf(tile[c][r]);
  }
}

// -------- batched 1024x1024 transpose-cast: z selects (src,dst) pair --------
struct TCBatch { const float* src[12]; unsigned short* dst[12]; };
__global__ __launch_bounds__(256) void k_tcast_b(TCBatch p) {
  __shared__ float tile[32][33];
  const float* src = p.src[blockIdx.z];
  unsigned short* dst = p.dst[blockIdx.z];
  int gx = blockIdx.x * 32, gy = blockIdx.y * 32;
  int t = threadIdx.x;
  int c = t & 31, r0 = t >> 5;
#pragma unroll
  for (int i = 0; i < 4; i++) {
    int r = r0 + i * 8;
    tile[r][c] = src[(size_t)(gy + r) * 1024 + gx + c];
  }
  __syncthreads();
#pragma unroll
  for (int i = 0; i < 4; i++) {
    int r = r0 + i * 8;
    dst[(size_t)(gx + r) * 1024 + gy + c] = f2bf(tile[c][r]);
  }
}

// ---- folded bias: out[n] = bv[n] + sum_j bk[j]*wv[j][n]  (f32, 1024 wide) ----
__global__ __launch_bounds__(256) void k_bfold(const float* __restrict__ bk,
                                               const float* __restrict__ wv,
                                               const float* __restrict__ bv,
                                               float* __restrict__ out) {
  int n = blockIdx.x * 256 + threadIdx.x;
  float acc = bv[n];
#pragma unroll 8
  for (int j = 0; j < 1024; j++) acc += bk[j] * wv[(size_t)j * 1024 + n];
  out[n] = acc;
}

// ---- concat two 1024-f32 vectors into out[0..2047] ----
__global__ __launch_bounds__(256) void k_cpb(const float* __restrict__ a,
                                             const float* __restrict__ b,
                                             float* __restrict__ out) {
  int t = blockIdx.x * 256 + threadIdx.x;
  out[t] = a[t];
  out[1024 + t] = b[t];
}

// ---- cs-fold: BtQK[n=(h*16+s)][k] = sum_e wqT[h*64+e][k]*K[s][h*64+e]; bqk[n]=bq.K ----
__global__ __launch_bounds__(256) void k_wqk(const unsigned short* __restrict__ wqT,
                                             const float* __restrict__ bq,
                                             const unsigned short* __restrict__ Kcs,
                                             unsigned short* __restrict__ BtQK,
                                             float* __restrict__ bqk) {
  int n = blockIdx.x, h = n >> 4, s = n & 15, t = threadIdx.x;
  if (s >= 10) {
    ((u16x4*)(BtQK + (size_t)n * 1024))[t] = u16x4{0, 0, 0, 0};
    if (t == 0) bqk[n] = 0.f;
    return;
  }
  float acc[4] = {0.f, 0.f, 0.f, 0.f};
  for (int e = 0; e < 64; e++) {
    float kv = bf2f(Kcs[s * 1024 + h * 64 + e]);
    u16x4 rv = ((const u16x4*)(wqT + (size_t)(h * 64 + e) * 1024))[t];
#pragma unroll
    for (int i = 0; i < 4; i++) acc[i] += bf2f(rv[i]) * kv;
  }
  u16x4 o;
#pragma unroll
  for (int i = 0; i < 4; i++) o[i] = f2bf(acc[i]);
  ((u16x4*)(BtQK + (size_t)n * 1024))[t] = o;
  if (t == 0) {
    float b = 0.f;
    for (int e = 0; e < 64; e++) b += bq[h * 64 + e] * bf2f(Kcs[s * 1024 + h * 64 + e]);
    bqk[n] = b;
  }
}

// ---- entmax-1.5 over 10 stored patterns, fully in registers (thread = (row,head)) ----
__global__ __launch_bounds__(256) void k_entmax10(const unsigned short* __restrict__ SC,
                                                  unsigned short* __restrict__ A) {
  int t = threadIdx.x;
  int m = blockIdx.x * 16 + (t >> 4), h = t & 15;
  const unsigned short* p = SC + (size_t)m * 256 + h * 16;
  float xs[10], mx = -1e30f;
#pragma unroll
  for (int s = 0; s < 10; s++) { xs[s] = bf2f(p[s]) * 0.0625f; mx = fmaxf(mx, xs[s]); }
  float lo = mx - 1.f, hi = mx - 0.31622776601683794f;  // d^-0.5, d=10
#pragma unroll 1
  for (int it = 0; it < 26; it++) {
    float mid = 0.5f * (lo + hi);
    float f = 0.f;
#pragma unroll
    for (int s = 0; s < 10; s++) { float dd = fmaxf(xs[s] - mid, 0.f); f += dd * dd; }
    bool gt = f > 1.f;
    lo = gt ? mid : lo;
    hi = gt ? hi : mid;
  }
  float tau = 0.5f * (lo + hi), ps = 0.f;
#pragma unroll
  for (int s = 0; s < 10; s++) { float dd = fmaxf(xs[s] - tau, 0.f); xs[s] = dd * dd; ps += xs[s]; }
  float r = 1.f / ps;
  unsigned short* q = A + (size_t)m * 256 + h * 16;
  u16x4 o0, o1, o2, o3;
#pragma unroll
  for (int i = 0; i < 4; i++) o0[i] = f2bf(xs[i] * r);
#pragma unroll
  for (int i = 0; i < 4; i++) o1[i] = f2bf(xs[4 + i] * r);
  o2[0] = f2bf(xs[8] * r); o2[1] = f2bf(xs[9] * r); o2[2] = 0; o2[3] = 0;
  o3[0] = o3[1] = o3[2] = o3[3] = 0;
  ((u16x4*)q)[0] = o0; ((u16x4*)q)[1] = o1; ((u16x4*)q)[2] = o2; ((u16x4*)q)[3] = o3;
}

// ---- PV + Hopfield "mix": out_mix[(b*32+ln)][c] = sum_s A[b,h,l,s] * V[s][h*64+d]
// with h = ln>>1, l = (ln&1)*16 + (c>>6), d = c&63.  One block per output row.
__global__ __launch_bounds__(256) void k_pvmix(const unsigned short* __restrict__ A,
                                               const unsigned short* __restrict__ Vcs,
                                               unsigned short* __restrict__ Out) {
  __shared__ float Vs[10][64];
  __shared__ float Asm[16][10];
  const int row = blockIdx.x;
  const int b = row >> 5, ln = row & 31;
  const int h = ln >> 1, lbase = (ln & 1) * 16;
  const int t = threadIdx.x;
  if (t < 160) {
    int j = t / 10, s = t - j * 10;
    Asm[j][s] = bf2f(A[((size_t)(b * 32 + lbase + j)) * 256 + h * 16 + s]);
  }
  for (int idx = t; idx < 640; idx += 256) {
    int s = idx >> 6, d = idx & 63;
    Vs[s][d] = bf2f(Vcs[s * 1024 + h * 64 + d]);
  }
  __syncthreads();
  const int j = t >> 4, d0 = (t & 15) * 4;
  float acc[4] = {0.f, 0.f, 0.f, 0.f};
#pragma unroll
  for (int s = 0; s < 10; s++) {
    float a = Asm[j][s];
#pragma unroll
    for (int i = 0; i < 4; i++) acc[i] += a * Vs[s][d0 + i];
  }
  u16x4 o;
#pragma unroll
  for (int i = 0; i < 4; i++) o[i] = f2bf(acc[i]);
  ((u16x4*)(Out + (size_t)row * 1024))[t] = o;
}

// ======== r11-proven 8-phase-family GEMM: 256x256, BK=64 + T1 XCD-chunked swizzle ========
template <bool GELU>
__global__ __launch_bounds__(512, 2) void k_gemm8(const unsigned short* __restrict__ A,
                                                  const unsigned short* __restrict__ Bt,
                                                  const float* __restrict__ bias,
                                                  unsigned short* __restrict__ C,
                                                  int M, int N, int K) {
  __shared__ unsigned short As[2][256 * 64];
  __shared__ unsigned short Bs[2][256 * 64];
  // T1: XCD-chunked bijective block swizzle (identity when nwg%8 != 0)
  int nwg = gridDim.x * gridDim.y;
  int lin = blockIdx.y * gridDim.x + blockIdx.x;
  int swz = (nwg & 7) ? lin : ((lin & 7) * (nwg >> 3) + (lin >> 3));
  const int rowA0 = (swz / gridDim.x) * 256, colB0 = (swz % gridDim.x) * 256;
  const int t = threadIdx.x, w = t >> 6, lane = t & 63;
  const int wm = w >> 2, wn = w & 3;
  const int g = lane >> 4, ra = lane & 15;
  const int koff0 = (((0 * 4 + g) ^ (ra & 7)) * 8);
  const int koff1 = (((1 * 4 + g) ^ (ra & 7)) * 8);
  const int srow = w * 8 + (lane >> 3);
  const int schunk = ((lane & 7) ^ ((lane >> 3) & 7)) * 8;

  f32x4 acc[8][4] = {};

  auto stageA = [&](int buf, int kk) {
#pragma unroll
    for (int gq = 0; gq < 4; gq++)
      gl2lds16(A + (size_t)(rowA0 + gq * 64 + srow) * K + kk + schunk,
               &As[buf][gq * 4096 + w * 512]);
  };
  auto stageB = [&](int buf, int kk) {
#pragma unroll
    for (int gq = 0; gq < 4; gq++)
      gl2lds16(Bt + (size_t)(colB0 + gq * 64 + srow) * K + kk + schunk,
               &Bs[buf][gq * 4096 + w * 512]);
  };

  const int NT = K >> 6;
  stageA(0, 0); stageB(0, 0);
  if (NT > 1) { stageA(1, 64); stageB(1, 64); }
  if (NT > 1) asm volatile("s_waitcnt vmcnt(8)" ::: "memory");
  else        asm volatile("s_waitcnt vmcnt(0)" ::: "memory");
  __builtin_amdgcn_sched_barrier(0);
  __builtin_amdgcn_s_barrier();

  bf16x8 aH[4][2], bH[2][2][2];
  const int arow0 = wm * 128, brow0 = wn * 64;
  for (int j = 0; j < NT; ++j) {
    const int buf = j & 1;
    const unsigned short* Ab = &As[buf][0];
    const unsigned short* Bb = &Bs[buf][0];
    // phase 0
#pragma unroll
    for (int fr = 0; fr < 4; fr++) {
      aH[fr][0] = *(const bf16x8*)&Ab[(arow0 + fr * 16 + ra) * 64 + koff0];
      aH[fr][1] = *(const bf16x8*)&Ab[(arow0 + fr * 16 + ra) * 64 + koff1];
    }
#pragma unroll
    for (int fc = 0; fc < 2; fc++) {
      bH[0][fc][0] = *(const bf16x8*)&Bb[(brow0 + fc * 16 + ra) * 64 + koff0];
      bH[0][fc][1] = *(const bf16x8*)&Bb[(brow0 + fc * 16 + ra) * 64 + koff1];
    }
    __builtin_amdgcn_sched_barrier(0);
    __builtin_amdgcn_s_barrier();
    __builtin_amdgcn_sched_barrier(0);
    __builtin_amdgcn_s_setprio(1);
#pragma unroll
    for (int fr = 0; fr < 4; fr++)
#pragma unroll
      for (int fc = 0; fc < 2; fc++)
#pragma unroll
        for (int ks = 0; ks < 2; ks++)
          acc[fr][fc] = __builtin_amdgcn_mfma_f32_16x16x32_bf16(aH[fr][ks], bH[0][fc][ks], acc[fr][fc], 0, 0, 0);
    __builtin_amdgcn_s_setprio(0);
    __builtin_amdgcn_sched_barrier(0);
    __builtin_amdgcn_s_barrier();
    // phase 1
#pragma unroll
    for (int fc = 0; fc < 2; fc++) {
      bH[1][fc][0] = *(const bf16x8*)&Bb[(brow0 + 32 + fc * 16 + ra) * 64 + koff0];
      bH[1][fc][1] = *(const bf16x8*)&Bb[(brow0 + 32 + fc * 16 + ra) * 64 + koff1];
    }
    __builtin_amdgcn_sched_barrier(0);
    __builtin_amdgcn_s_barrier();
    __builtin_amdgcn_sched_barrier(0);
    __builtin_amdgcn_s_setprio(1);
#pragma unroll
    for (int fr = 0; fr < 4; fr++)
#pragma unroll
      for (int fc = 0; fc < 2; fc++)
#pragma unroll
        for (int ks = 0; ks < 2; ks++)
          acc[fr][2 + fc] = __builtin_amdgcn_mfma_f32_16x16x32_bf16(aH[fr][ks], bH[1][fc][ks], acc[fr][2 + fc], 0, 0, 0);
    __builtin_amdgcn_s_setprio(0);
    __builtin_amdgcn_sched_barrier(0);
    __builtin_amdgcn_s_barrier();
    // phase 2: stage B(j+2) into same buf (B(j) reads done)
#pragma unroll
    for (int fr = 0; fr < 4; fr++) {
      aH[fr][0] = *(const bf16x8*)&Ab[(arow0 + 64 + fr * 16 + ra) * 64 + koff0];
      aH[fr][1] = *(const bf16x8*)&Ab[(arow0 + 64 + fr * 16 + ra) * 64 + koff1];
    }
    if (j + 2 < NT) stageB(buf, (j + 2) << 6);
    __builtin_amdgcn_sched_barrier(0);
    __builtin_amdgcn_s_barrier();
    __builtin_amdgcn_sched_barrier(0);
    __builtin_amdgcn_s_setprio(1);
#pragma unroll
    for (int fr = 0; fr < 4; fr++)
#pragma unroll
      for (int fc = 0; fc < 2; fc++)
#pragma unroll
        for (int ks = 0; ks < 2; ks++)
          acc[4 + fr][fc] = __builtin_amdgcn_mfma_f32_16x16x32_bf16(aH[fr][ks], bH[0][fc][ks], acc[4 + fr][fc], 0, 0, 0);
    __builtin_amdgcn_s_setprio(0);
    __builtin_amdgcn_sched_barrier(0);
    __builtin_amdgcn_s_barrier();
    // phase 3: stage A(j+2); counted boundary
    if (j + 2 < NT) stageA(buf, (j + 2) << 6);
    __builtin_amdgcn_sched_barrier(0);
    __builtin_amdgcn_s_setprio(1);
#pragma unroll
    for (int fr = 0; fr < 4; fr++)
#pragma unroll
      for (int fc = 0; fc < 2; fc++)
#pragma unroll
        for (int ks = 0; ks < 2; ks++)
          acc[4 + fr][2 + fc] = __builtin_amdgcn_mfma_f32_16x16x32_bf16(aH[fr][ks], bH[1][fc][ks], acc[4 + fr][2 + fc], 0, 0, 0);
    __builtin_amdgcn_s_setprio(0);
    if (j + 1 < NT) {
      if (j + 2 < NT) asm volatile("s_waitcnt vmcnt(8)" ::: "memory");
      else            asm volatile("s_waitcnt vmcnt(0)" ::: "memory");
    }
    __builtin_amdgcn_sched_barrier(0);
    __builtin_amdgcn_s_barrier();
  }
  asm volatile("s_waitcnt vmcnt(0) lgkmcnt(0)" ::: "memory");
  __builtin_amdgcn_s_barrier();

  unsigned short* Ep = &As[0][0] + w * 1024;
  const int grow0 = rowA0 + wm * 128;
  const int gcol0 = colB0 + wn * 64;
  float bv[4];
#pragma unroll
  for (int n = 0; n < 4; n++) bv[n] = bias ? bias[gcol0 + n * 16 + ra] : 0.f;
  const int rdrow = lane >> 3, rg = lane & 7;
#pragma unroll
  for (int m = 0; m < 8; m++) {
#pragma unroll
    for (int n = 0; n < 4; n++)
#pragma unroll
      for (int i = 0; i < 4; i++) {
        int r = g * 4 + i;
        float v = acc[m][n][i] + bv[n];
        if (GELU) v = 0.5f * v * (1.f + erff(v * 0.70710678118654752f));
        Ep[r * 64 + ((ra + n * 16) ^ ((r & 7) << 3))] = f2bf(v);
      }
    asm volatile("s_waitcnt lgkmcnt(0)" ::: "memory");
    __builtin_amdgcn_sched_barrier(0);
#pragma unroll
    for (int p = 0; p < 2; p++) {
      int rr = p * 8 + rdrow;
      bf16x8 val = *(const bf16x8*)&Ep[rr * 64 + ((rg ^ (rr & 7)) << 3)];
      *(bf16x8*)&C[(size_t)(grow0 + m * 16 + rr) * N + gcol0 + rg * 8] = val;
    }
    asm volatile("s_waitcnt lgkmcnt(0)" ::: "memory");
  }
}

// ======== small MFMA GEMM (folds + skinny cs GEMMs): 128^2 tile, ring-3 ========
__global__ __launch_bounds__(256) void k_gemmS(const unsigned short* __restrict__ A,
                                               const unsigned short* __restrict__ Bt,
                                               const float* __restrict__ bias,
                                               unsigned short* __restrict__ C,
                                               int M, int N, int K) {
  __shared__ unsigned short As[3][128 * 32];
  __shared__ unsigned short Bs[3][128 * 32];
  const int rowA0 = blockIdx.y * 128, colB0 = blockIdx.x * 128;
  const int t = threadIdx.x, w = t >> 6, lane = t & 63;
  const int wr = w >> 1, wc = w & 1;
  const int srow = w * 16 + (lane >> 2);
  const int schunk = (lane & 3) ^ ((lane >> 3) & 3);
  const unsigned short* pa = A + (size_t)(rowA0 + srow) * K + schunk * 8;
  const unsigned short* pb = Bt + (size_t)(colB0 + srow) * K + schunk * 8;
  const size_t row64 = (size_t)64 * K;
  f32x4 acc[4][4] = {};
  const int g = lane >> 4, ra = lane & 15;
  const int gp8 = (g ^ ((ra >> 1) & 3)) * 8;
  auto stage = [&](int buf, int kk) {
    gl2lds16(pa + kk, &As[buf][w * 512]);
    gl2lds16(pa + row64 + kk, &As[buf][2048 + w * 512]);
    gl2lds16(pb + kk, &Bs[buf][w * 512]);
    gl2lds16(pb + row64 + kk, &Bs[buf][2048 + w * 512]);
  };
  const int NT = K >> 5;
  stage(0, 0);
  if (NT > 1) stage(1, 32);
  int cur = 0;
  for (int j = 0; j < NT; ++j) {
    if (j + 1 < NT) asm volatile("s_waitcnt vmcnt(4)" ::: "memory");
    else            asm volatile("s_waitcnt vmcnt(0)" ::: "memory");
    __syncthreads();
    if (j + 2 < NT) { int nb = cur + 2; if (nb >= 3) nb -= 3; stage(nb, (j + 2) * 32); }
    bf16x8 af[4], bfr[4];
#pragma unroll
    for (int m = 0; m < 4; m++)
      af[m] = *(const bf16x8*)&As[cur][(wr * 64 + m * 16 + ra) * 32 + gp8];
#pragma unroll
    for (int n = 0; n < 4; n++)
      bfr[n] = *(const bf16x8*)&Bs[cur][(wc * 64 + n * 16 + ra) * 32 + gp8];
#pragma unroll
    for (int m = 0; m < 4; m++)
#pragma unroll
      for (int n = 0; n < 4; n++)
        acc[m][n] = __builtin_amdgcn_mfma_f32_16x16x32_bf16(af[m], bfr[n], acc[m][n], 0, 0, 0);
    __syncthreads();
    cur += 1; if (cur >= 3) cur -= 3;
  }
  const int cr = g * 4, cc = ra;
#pragma unroll
  for (int m = 0; m < 4; m++) {
    int grow = rowA0 + wr * 64 + m * 16 + cr;
#pragma unroll
    for (int n = 0; n < 4; n++) {
      int gcol = colB0 + wc * 64 + n * 16 + cc;
      float bvv = bias ? bias[gcol] : 0.f;
#pragma unroll
      for (int i = 0; i < 4; i++)
        C[(size_t)(grow + i) * N + gcol] = f2bf(acc[m][n][i] + bvv);
    }
  }
}

// ---------------- small GEMM (M<=10): C[Mr][1024] = A[Mr][1024] * Wt^T + bias ----------------
__global__ __launch_bounds__(256) void k_gemm10(const unsigned short* __restrict__ A,
                                                const unsigned short* __restrict__ Bt,
                                                const float* __restrict__ bias,
                                                unsigned short* __restrict__ C) {
  __shared__ float af[1024];
  int m = blockIdx.x, nb = blockIdx.y;
  int t = threadIdx.x;
#pragma unroll
  for (int i = 0; i < 4; i++) af[t * 4 + i] = bf2f(A[(size_t)m * 1024 + t * 4 + i]);
  __syncthreads();
  int w = t >> 6, lane = t & 63;
  for (int n = nb * 64 + w; n < nb * 64 + 64; n += 4) {
    const unsigned short* brow = Bt + (size_t)n * 1024 + lane * 16;
    float acc = 0.f;
#pragma unroll
    for (int j = 0; j < 16; j++) acc += af[lane * 16 + j] * bf2f(brow[j]);
#pragma unroll
    for (int o = 32; o; o >>= 1) acc += __shfl_xor(acc, o);
    if (lane == 0) C[(size_t)m * 1024 + n] = f2bf(acc + bias[n]);
  }
}

// ---------------- entmax-1.5 attention, MFMA version (RS = input row stride) ----------------
template <int L, int S, bool SHARED>
__global__ __launch_bounds__(256) void k_attn(const unsigned short* __restrict__ Q,
                                              const unsigned short* __restrict__ Kb,
                                              const unsigned short* __restrict__ Vb,
                                              unsigned short* __restrict__ Out, int RS) {
  constexpr int SP = (S <= 32) ? 32 : 64;
  constexpr int QST = 72;
  constexpr int VST = SP + 8;
  constexpr int CST = SP + 4;
  __shared__ unsigned short Qs[L * QST];
  __shared__ unsigned short Ks[SP * QST];
  __shared__ unsigned short Vt[64 * VST];
  __shared__ float Sc[L * CST];
  __shared__ float Rps[L];
  const int blk = blockIdx.x, batch = blk >> 4, h = blk & 15;
  const int t = threadIdx.x, w = t >> 6, lane = t & 63;
  for (int c = t; c < L * 8; c += 256) {
    int r = c >> 3, ch = (c & 7) * 8;
    *(i32x4*)&Qs[r * QST + ch] =
        *(const i32x4*)&Q[((size_t)(batch * L + r)) * RS + h * 64 + ch];
  }
  for (int c = t; c < SP * 8; c += 256) {
    int r = c >> 3, ch = (c & 7) * 8;
    i32x4 v = {0, 0, 0, 0};
    if (r < S) {
      size_t rb = SHARED ? (size_t)r : (size_t)(batch * S + r);
      v = *(const i32x4*)&Kb[rb * RS + h * 64 + ch];
    }
    *(i32x4*)&Ks[r * QST + ch] = v;
  }
  for (int c = t; c < SP * 64; c += 256) {
    int s = c >> 6, e = c & 63;
    unsigned short v = 0;
    if (s < S) {
      size_t rb = SHARED ? (size_t)s : (size_t)(batch * S + s);
      v = Vb[rb * RS + h * 64 + e];
    }
    Vt[e * VST + s] = v;
  }
  __syncthreads();
  const int ka = (lane >> 4) * 8, ra = lane & 15;
  const int cr = (lane >> 4) * 4, cc = lane & 15;
  constexpr int NT = SP / 16, TT = (L / 16) * NT;
  for (int tt = w; tt < TT; tt += 4) {
    int m = tt / NT, n = tt % NT;
    f32x4 a = {0.f, 0.f, 0.f, 0.f};
#pragma unroll
    for (int ks = 0; ks < 2; ks++) {
      bf16x8 af = *(const bf16x8*)&Qs[(m * 16 + ra) * QST + ks * 32 + ka];
      bf16x8 bf = *(const bf16x8*)&Ks[(n * 16 + ra) * QST + ks * 32 + ka];
      a = __builtin_amdgcn_mfma_f32_16x16x32_bf16(af, bf, a, 0, 0, 0);
    }
#pragma unroll
    for (int i = 0; i < 4; i++)
      Sc[(m * 16 + cr + i) * CST + n * 16 + cc] = a[i] * 0.0625f;
  }
  __syncthreads();
  constexpr int G = 256 / L, RW = 64 / G, SL = SP / G;
  const int row = w * RW + lane / G, sub = lane % G;
  float xs[SL];
#pragma unroll
  for (int j = 0; j < SL; j++) {
    int s = sub * SL + j;
    float v = Sc[row * CST + s];
    if (S < SP && s >= S) v = -1e30f;
    xs[j] = v;
  }
  float mx = xs[0];
#pragma unroll
  for (int j = 1; j < SL; j++) mx = fmaxf(mx, xs[j]);
#pragma unroll
  for (int o = G / 2; o; o >>= 1) mx = fmaxf(mx, __shfl_xor(mx, o));
  const float hoff = (S == 64) ? 0.125f : (S == 32) ? 0.17677669529663687f : 0.31622776601683794f;
  float lo = mx - 1.f, hi = mx - hoff;
#pragma unroll 1
  for (int it = 0; it < 26; it++) {
    float mid = 0.5f * (lo + hi);
    float f = 0.f;
#pragma unroll
    for (int j = 0; j < SL; j++) { float dd = fmaxf(xs[j] - mid, 0.f); f += dd * dd; }
#pragma unroll
    for (int o = G / 2; o; o >>= 1) f += __shfl_xor(f, o);
    bool gt = f > 1.f;
    lo = gt ? mid : lo;
    hi = gt ? hi : mid;
  }
  float tau = 0.5f * (lo + hi);
  float ps = 0.f;
#pragma unroll
  for (int j = 0; j < SL; j++) { float dd = fmaxf(xs[j] - tau, 0.f); xs[j] = dd * dd; ps += xs[j]; }
#pragma unroll
  for (int o = G / 2; o; o >>= 1) ps += __shfl_xor(ps, o);
  if (sub == 0) Rps[row] = 1.f / ps;
  unsigned short* Pb = Qs;
#pragma unroll
  for (int j = 0; j < SL; j += 4) {
    u16x4 pv;
#pragma unroll
    for (int jj = 0; jj < 4; jj++) pv[jj] = f2bf(xs[j + jj]);
    *(u16x4*)&Pb[row * VST + sub * SL + j] = pv;
  }
  __syncthreads();
  constexpr int TT2 = (L / 16) * 4;
  for (int tt = w; tt < TT2; tt += 4) {
    int m = tt >> 2, n = tt & 3;
    f32x4 a = {0.f, 0.f, 0.f, 0.f};
#pragma unroll
    for (int ks = 0; ks < SP / 32; ks++) {
      bf16x8 af = *(const bf16x8*)&Pb[(m * 16 + ra) * VST + ks * 32 + ka];
      bf16x8 bf = *(const bf16x8*)&Vt[(n * 16 + ra) * VST + ks * 32 + ka];
      a = __builtin_amdgcn_mfma_f32_16x16x32_bf16(af, bf, a, 0, 0, 0);
    }
#pragma unroll
    for (int i = 0; i < 4; i++) {
      int l = m * 16 + cr + i, e = n * 16 + cc;
      float val = a[i] * Rps[l];
      int l_new = h * (L / 16) + (l >> 4);
      int cg = (l & 15) * 64 + e;
      Out[((size_t)(batch * L + l_new)) * 1024 + cg] = f2bf(val);
    }
  }
}

// ---------------- LayerNorm(a+b) * g + be, optional row permutation / f32 out ----------------
template <int MODE, bool F32OUT>
__global__ __launch_bounds__(256) void k_ln(const unsigned short* __restrict__ a,
                                            const unsigned short* __restrict__ b,
                                            const float* __restrict__ g,
                                            const float* __restrict__ be,
                                            void* __restrict__ outp) {
  __shared__ float red[8];
  int r = blockIdx.x, t = threadIdx.x;
  size_t base = (size_t)r * 1024 + t * 4;
  u16x4 av = *(const u16x4*)(a + base);
  u16x4 bv = *(const u16x4*)(b + base);
  float x[4];
  float s = 0.f, ss = 0.f;
#pragma unroll
  for (int i = 0; i < 4; i++) {
    x[i] = bf2f(av[i]) + bf2f(bv[i]);
    s += x[i]; ss += x[i] * x[i];
  }
#pragma unroll
  for (int o = 32; o; o >>= 1) { s += __shfl_xor(s, o); ss += __shfl_xor(ss, o); }
  int w = t >> 6;
  if ((t & 63) == 0) { red[w] = s; red[4 + w] = ss; }
  __syncthreads();
  s = red[0] + red[1] + red[2] + red[3];
  ss = red[4] + red[5] + red[6] + red[7];
  float mean = s * (1.f / 1024.f);
  float var = ss * (1.f / 1024.f) - mean * mean;
  float rstd = rsqrtf(var + 1e-5f);
  int orow;
  if (MODE == 0) orow = r;
  else if (MODE == 1) { int bi = r >> 11, rem = r & 2047; int tt = rem >> 6, sd = rem & 63; orow = (bi << 11) + sd * 32 + tt; }
  else { int bi = r >> 11, rem = r & 2047; int sd = rem >> 5, tt = rem & 31; orow = (bi << 11) + tt * 64 + sd; }
  size_t ob = (size_t)orow * 1024 + t * 4;
  if (F32OUT) {
    f32x4 y;
#pragma unroll
    for (int i = 0; i < 4; i++) y[i] = (x[i] - mean) * rstd * g[t * 4 + i] + be[t * 4 + i];
    *(f32x4*)((float*)outp + ob) = y;
  } else {
    u16x4 y;
#pragma unroll
    for (int i = 0; i < 4; i++) y[i] = f2bf((x[i] - mean) * rstd * g[t * 4 + i] + be[t * 4 + i]);
    *(u16x4*)((unsigned short*)outp + ob) = y;
  }
}

// =======================================================================================

extern "C" void kernel_launch(void* const* d_in, const int* in_sizes, int n_in,
                              void* d_out, int out_size, void* d_ws, size_t ws_size,
                              hipStream_t stream) {
  const int M = 16384;
  if (n_in < 43 || in_sizes[0] != 16777216 || in_sizes[25] != 10240 || in_sizes[34] != 4194304) {
    fprintf(stderr, "kernel_launch: unexpected input layout (n_in=%d)\n", n_in);
    return;
  }
  const float* x = (const float*)d_in[0];
  const float* w[3][4]; const float* bia[3][4];
  for (int p = 0; p < 3; p++) {
    w[p][0] = (const float*)d_in[1 + 8 * p + 0]; bia[p][0] = (const float*)d_in[1 + 8 * p + 1];
    w[p][1] = (const float*)d_in[1 + 8 * p + 2]; bia[p][1] = (const float*)d_in[1 + 8 * p + 3];
    w[p][2] = (const float*)d_in[1 + 8 * p + 4]; bia[p][2] = (const float*)d_in[1 + 8 * p + 5];
    w[p][3] = (const float*)d_in[1 + 8 * p + 6]; bia[p][3] = (const float*)d_in[1 + 8 * p + 7];
  }
  const float* cs_key = (const float*)d_in[25];
  const float* ng[4]; const float* nb[4];
  for (int i = 0; i < 4; i++) { ng[i] = (const float*)d_in[26 + 2 * i]; nb[i] = (const float*)d_in[27 + 2 * i]; }
  const float* m_w1[2]; const float* m_b1[2]; const float* m_w2[2]; const float* m_b2[2];
  for (int i = 0; i < 2; i++) {
    m_w1[i] = (const float*)d_in[34 + 4 * i]; m_b1[i] = (const float*)d_in[35 + 4 * i];
    m_w2[i] = (const float*)d_in[36 + 4 * i]; m_b2[i] = (const float*)d_in[37 + 4 * i];
  }

  // ---- workspace ----
  char* base = (char*)d_ws; size_t off = 0;
  auto alloc = [&](size_t bytes) -> void* {
    off = (off + 255) & ~(size_t)255;
    void* p = base + off; off += bytes; return p;
  };
  const size_t W1M = (size_t)1024 * 1024;
  unsigned short* W3ct = (unsigned short*)alloc(3 * W1M * 2);  // [wqT; wkT; wkvT]
  unsigned short* W3hp = (unsigned short*)alloc(3 * W1M * 2);
  unsigned short* Woct = (unsigned short*)alloc(W1M * 2);
  unsigned short* Wohp = (unsigned short*)alloc(W1M * 2);
  unsigned short* Wocs = (unsigned short*)alloc(W1M * 2);
  unsigned short* Wqcs = (unsigned short*)alloc(W1M * 2);
  unsigned short* Wkcs = (unsigned short*)alloc(W1M * 2);
  unsigned short* Wvcs = (unsigned short*)alloc(W1M * 2);
  unsigned short* Wm1u = (unsigned short*)alloc((size_t)4096 * 1024 * 2);
  unsigned short* Wm1d = (unsigned short*)alloc((size_t)1024 * 4096 * 2);
  unsigned short* Wm2u = (unsigned short*)alloc((size_t)4096 * 1024 * 2);
  unsigned short* Wm2d = (unsigned short*)alloc((size_t)1024 * 4096 * 2);
  unsigned short* BtQK = (unsigned short*)alloc((size_t)256 * 1024 * 2);
  float* bqk = (float*)alloc(256 * 4);
  float* b3ct = (float*)alloc(3072 * 4);
  float* b3hp = (float*)alloc(3072 * 4);
  unsigned short* KeyB = (unsigned short*)alloc((size_t)10 * 1024 * 2);
  unsigned short* Kcs = (unsigned short*)alloc((size_t)10 * 1024 * 2);
  unsigned short* Vcs = (unsigned short*)alloc((size_t)10 * 1024 * 2);
  unsigned short* S[6];
  for (int i = 0; i < 6; i++) S[i] = (unsigned short*)alloc((size_t)M * 1024 * 2);
  if (off > ws_size) {
    fprintf(stderr, "kernel_launch: ws too small: need %zu have %zu\n", off, ws_size);
    return;
  }
  // fold scratch aliased into S1 (dead during prep)
  unsigned short* Wvt_ct = S[1];
  unsigned short* Wraw_ct = S[1] + W1M;
  unsigned short* Wvt_hp = S[1] + 2 * W1M;
  unsigned short* Wraw_hp = S[1] + 3 * W1M;

  auto gemm8 = [&](const unsigned short* Ap, const unsigned short* Bt, const float* bi,
                   unsigned short* Cp, int Mm, int Nn, int Kk, bool gelu) {
    dim3 gg(Nn / 256, Mm / 256);
    if (gelu) k_gemm8<true><<<gg, 512, 0, stream>>>(Ap, Bt, bi, Cp, Mm, Nn, Kk);
    else      k_gemm8<false><<<gg, 512, 0, stream>>>(Ap, Bt, bi, Cp, Mm, Nn, Kk);
  };

  // ---- weight prep (batched 1024^2 transposes: 12 -> 1 launch) ----
  TCBatch tcb;
  tcb.src[0] = w[0][0];  tcb.dst[0] = W3ct;
  tcb.src[1] = w[0][1];  tcb.dst[1] = W3ct + W1M;
  tcb.src[2] = w[2][0];  tcb.dst[2] = W3hp;
  tcb.src[3] = w[2][1];  tcb.dst[3] = W3hp + W1M;
  tcb.src[4] = w[0][3];  tcb.dst[4] = Woct;
  tcb.src[5] = w[2][3];  tcb.dst[5] = Wohp;
  tcb.src[6] = w[1][3];  tcb.dst[6] = Wocs;
  tcb.src[7] = w[1][0];  tcb.dst[7] = Wqcs;
  tcb.src[8] = w[1][1];  tcb.dst[8] = Wkcs;
  tcb.src[9] = w[1][2];  tcb.dst[9] = Wvcs;
  tcb.src[10] = w[0][2]; tcb.dst[10] = Wvt_ct;
  tcb.src[11] = w[2][2]; tcb.dst[11] = Wvt_hp;
  k_tcast_b<<<dim3(32, 32, 12), 256, 0, stream>>>(tcb);
  k_tcast<<<dim3(128, 32), 256, 0, stream>>>(m_w1[0], Wm1u, 1024, 4096);
  k_tcast<<<dim3(32, 128), 256, 0, stream>>>(m_w2[0], Wm1d, 4096, 1024);
  k_tcast<<<dim3(128, 32), 256, 0, stream>>>(m_w1[1], Wm2u, 1024, 4096);
  k_tcast<<<dim3(32, 128), 256, 0, stream>>>(m_w2[1], Wm2d, 4096, 1024);
  k_cast<<<1024, 256, 0, stream>>>(w[0][1], Wraw_ct, 262144);
  k_cast<<<1024, 256, 0, stream>>>(w[2][1], Wraw_hp, 262144);
  k_cast<<<16384, 256, 0, stream>>>(x, S[0], 16777216 / 4);
  k_cast<<<10, 256, 0, stream>>>(cs_key, KeyB, 10240 / 4);
  // folded V weights (1024^3)
  k_gemmS<<<dim3(8, 8), 256, 0, stream>>>(Wvt_ct, Wraw_ct, nullptr, W3ct + 2 * W1M, 1024, 1024, 1024);
  k_gemmS<<<dim3(8, 8), 256, 0, stream>>>(Wvt_hp, Wraw_hp, nullptr, W3hp + 2 * W1M, 1024, 1024, 1024);
  // folded biases
  k_cpb<<<4, 256, 0, stream>>>(bia[0][0], bia[0][1], b3ct);
  k_bfold<<<4, 256, 0, stream>>>(bia[0][1], w[0][2], bia[0][2], b3ct + 2048);
  k_cpb<<<4, 256, 0, stream>>>(bia[2][0], bia[2][1], b3hp);
  k_bfold<<<4, 256, 0, stream>>>(bia[2][1], w[2][2], bia[2][2], b3hp + 2048);
  // cs stored patterns + scores fold
  k_gemm10<<<dim3(10, 16), 256, 0, stream>>>(KeyB, Wkcs, bia[1][1], Kcs);
  k_gemm10<<<dim3(10, 16), 256, 0, stream>>>(Kcs, Wvcs, bia[1][2], Vcs);
  k_wqk<<<256, 256, 0, stream>>>(Wqcs, bia[1][0], Kcs, BtQK, bqk);

  // ---- stage T (L=S=64 attention over seg) ----
  gemm8(S[0], W3ct, b3ct, S[1], M, 3072, 1024, false);                      // QKV -> S1..S3
  k_attn<64, 64, false><<<256 * 16, 256, 0, stream>>>(S[1], S[1] + 1024, S[1] + 2048, S[4], 3072);
  gemm8(S[4], Woct, bia[0][3], S[5], M, 1024, 1024, false);                 // enc -> S5
  k_ln<0, false><<<M, 256, 0, stream>>>(S[0], S[5], ng[0], nb[0], S[1]);    // D -> S1
  gemm8(S[1], Wm1u, m_b1[0], S[2], M, 4096, 1024, true);                    // H -> S2..S5
  gemm8(S[2], Wm1d, m_b2[0], S[0], M, 1024, 4096, false);                   // R -> S0
  k_ln<1, false><<<M, 256, 0, stream>>>(S[1], S[0], ng[1], nb[1], S[2]);    // S_in -> S2 (permuted)

  // ---- stage S (L=32) ----
  gemm8(S[2], W3hp, b3hp, S[3], M, 3072, 1024, false);                      // QKVhp -> S3..S5
  k_attn<32, 32, false><<<512 * 16, 256, 0, stream>>>(S[3], S[3] + 1024, S[3] + 2048, S[0], 3072);
  gemm8(S[0], Wohp, bia[2][3], S[1], M, 1024, 1024, false);                 // PH -> S1
  // cs-Hopfield: folded scores -> entmax10 -> PV in MIX layout -> out-proj
  k_gemmS<<<dim3(2, 128), 256, 0, stream>>>(S[2], BtQK, bqk, S[0], M, 256, 1024);   // SC -> S0[0:8M]
  k_entmax10<<<M / 16, 256, 0, stream>>>(S[0], S[0] + (size_t)M * 256);             // A -> S0[8M:16M]
  k_pvmix<<<M, 256, 0, stream>>>(S[0] + (size_t)M * 256, Vcs, S[3]);                // mix -> S3
  gemm8(S[3], Wocs, bia[1][3], S[4], M, 1024, 1024, false);                 // SH -> S4
  k_ln<0, false><<<M, 256, 0, stream>>>(S[4], S[1], ng[2], nb[2], S[0]);    // DE -> S0
  gemm8(S[0], Wm2u, m_b1[1], S[1], M, 4096, 1024, true);                    // H -> S1..S4
  gemm8(S[1], Wm2d, m_b2[1], S[5], M, 1024, 4096, false);                   // R2 -> S5
  k_ln<2, true><<<M, 256, 0, stream>>>(S[0], S[5], ng[3], nb[3], d_out);    // final LN+permute f32
}